// Round 8
// baseline (678.872 us; speedup 1.0000x reference)
//
#include <hip/hip_runtime.h>
#include <hip/hip_bf16.h>

// Problem constants (from reference): N=50000, E=800000, D=128, H=256, A=16
#define N_NODES 50000
#define N_EDGES 800000
#define DIM_D   128
#define DIM_H   256
#define DIM_A   16

typedef unsigned short u16;
typedef __attribute__((ext_vector_type(4))) float f4;
typedef __attribute__((ext_vector_type(8))) short s8;
typedef __attribute__((ext_vector_type(4))) short s4;
typedef __attribute__((ext_vector_type(2))) int i2;

__device__ __forceinline__ u16 f2bf(float f) {
    union { float f; unsigned u; } v; v.f = f;
    unsigned r = v.u + 0x7FFFu + ((v.u >> 16) & 1u);   // RNE
    return (u16)(r >> 16);
}
__device__ __forceinline__ float bf2f(u16 s) {
    union { unsigned u; float f; } v; v.u = ((unsigned)s) << 16; return v.f;
}
__device__ __forceinline__ s8 zero_s8() {
    s8 v;
#pragma unroll
    for (int i = 0; i < 8; i++) v[i] = 0;
    return v;
}
// HW-packed f32->bf16 via HIP intrinsics (compiler emits v_cvt_pk_bf16_f32; RNE, no inline asm)
__device__ __forceinline__ s4 pk_bf16x4(float a, float b, float c, float d) {
    __hip_bfloat162 h0 = __float22bfloat162_rn(make_float2(a, b));
    __hip_bfloat162 h1 = __float22bfloat162_rn(make_float2(c, d));
    s4 v;
    __builtin_memcpy(&v, &h0, 4);
    __builtin_memcpy(((char*)&v) + 4, &h1, 4);
    return v;
}
__device__ __forceinline__ u16 f2bf_hw(float f) {
    __hip_bfloat16 h = __float2bfloat16(f);
    u16 u; __builtin_memcpy(&u, &h, 2);
    return u;
}

// ---- PQ permuted column layout (within each 64-col group of a PQ row) ----
// stored[i*32 + q*8 + s*4 + j] = logical[(2i+s)*16 + q*4 + j]
__device__ __forceinline__ int pq_off(int mt, int q) {   // stored elem offset of logical chunk (mt, q)
    return (mt >> 2) * 64 + ((mt >> 1) & 1) * 32 + q * 8 + (mt & 1) * 4;
}

// ---------------- fused init: 8 weight transposes + bpq + cnt zero (was 11 launches) --------
__global__ __launch_bounds__(256) void k_init(const float* __restrict__ W1, const float* __restrict__ W2,
                                              const float* __restrict__ Wo1, const float* __restrict__ Wo2,
                                              const float* __restrict__ We1, const float* __restrict__ We2,
                                              const float* __restrict__ be1,
                                              u16* __restrict__ W1t, u16* __restrict__ W2t,
                                              u16* __restrict__ Wo1t, u16* __restrict__ Wo2t,
                                              u16* __restrict__ Wabt, u16* __restrict__ Wct,
                                              u16* __restrict__ We2t, float* __restrict__ bpq,
                                              int* __restrict__ cnt) {
    int idx = blockIdx.x * 256 + threadIdx.x;
    if (idx < 32768) {                 // W1 [128][256] -> W1t [256][128]
        int k = idx >> 8, n = idx & 255;
        W1t[n * 128 + k] = f2bf(W1[idx]);
    } else if (idx < 65536) {          // W2 [256][128] -> W2t [128][256]
        int r = idx - 32768, k = r >> 7, n = r & 127;
        W2t[n * 256 + k] = f2bf(W2[r]);
    } else if (idx < 98304) {          // Wo1 [128][256] -> Wo1t [256][128]
        int r = idx - 65536, k = r >> 8, n = r & 255;
        Wo1t[n * 128 + k] = f2bf(Wo1[r]);
    } else if (idx < 131072) {         // Wo2 [256][128] -> Wo2t [128][256]
        int r = idx - 98304, k = r >> 7, n = r & 127;
        Wo2t[n * 256 + k] = f2bf(Wo2[r]);
    } else if (idx < 163840) {         // Wa = We1 rows 0..127 -> Wabt[0..]
        int r = idx - 131072, k = r >> 8, n = r & 255;
        Wabt[n * 128 + k] = f2bf(We1[r]);
    } else if (idx < 196608) {         // Wb = We1 rows 128..255 -> Wabt[32768..]
        int r = idx - 163840, k = r >> 8, n = r & 255;
        Wabt[32768 + n * 128 + k] = f2bf(We1[32768 + r]);
    } else if (idx < 200704) {         // Wc = We1 rows 256..271 [16][256] -> Wct [256][16]
        int r = idx - 196608, k = r >> 8, n = r & 255;
        Wct[n * 16 + k] = f2bf(We1[65536 + r]);
    } else if (idx < 204800) {         // We2 [256][16] -> We2t [16][256]
        int r = idx - 200704, k = r >> 4, n = r & 15;
        We2t[n * 256 + k] = f2bf(We2[r]);
    } else if (idx < 205312) {         // bpq
        int i = idx - 204800;
        bpq[i] = (i < 256) ? be1[i] : 0.f;
    } else if (idx < 205312 + N_NODES) {
        cnt[idx - 205312] = 0;
    }
}

// ---------------- CSR build ----------------
__global__ __launch_bounds__(256) void k_count(const int* __restrict__ coli, int* __restrict__ cnt) {
    int e = blockIdx.x * 256 + threadIdx.x;
    if (e < N_EDGES) atomicAdd(&cnt[__builtin_nontemporal_load(&coli[e])], 1);
}

#define SCAN_C 49   // 1024 * 49 = 50176 >= N_NODES
__global__ __launch_bounds__(1024) void k_scan(const int* __restrict__ cnt, int* __restrict__ start,
                                               int* __restrict__ cursor) {
    __shared__ int ps[1024];
    int t = threadIdx.x;
    int base = t * SCAN_C;
    int sum = 0;
    for (int i = 0; i < SCAN_C; i++) {
        int idx = base + i;
        sum += (idx < N_NODES) ? cnt[idx] : 0;
    }
    ps[t] = sum;
    __syncthreads();
    for (int ofs = 1; ofs < 1024; ofs <<= 1) {
        int v = (t >= ofs) ? ps[t - ofs] : 0;
        __syncthreads();
        ps[t] += v;
        __syncthreads();
    }
    int run = (t > 0) ? ps[t - 1] : 0;
    for (int i = 0; i < SCAN_C; i++) {
        int idx = base + i;
        if (idx < N_NODES) {
            start[idx] = run;
            cursor[idx] = run;
            run += cnt[idx];
        }
    }
    if (t == 1023) start[N_NODES] = ps[1023];
}

// pack[slot] = {src_node, dinv[src]*dinv[dst]} bucketed by destination (dinv from cnt inline)
// eidx[slot] = {orig_edge, dst_node} (for CSR-ordered edge predictor)
__global__ __launch_bounds__(256) void k_fill(const int* __restrict__ rowi, const int* __restrict__ coli,
                                              const int* __restrict__ cnt,
                                              int* __restrict__ cursor, int2* __restrict__ pack,
                                              int2* __restrict__ eidx) {
    int e = blockIdx.x * 256 + threadIdx.x;
    if (e >= N_EDGES) return;
    int r = __builtin_nontemporal_load(&rowi[e]);
    int c = __builtin_nontemporal_load(&coli[e]);
    int slot = atomicAdd(&cursor[c], 1);
    float w = rsqrtf((float)(cnt[r] + 1)) * rsqrtf((float)(cnt[c] + 1));
    pack[slot] = make_int2(r, __float_as_int(w));
    eidx[slot] = make_int2(e, c);
}

// ---------------- fp32 -> bf16 cast (x table) ----------------
__global__ __launch_bounds__(256) void k_cast(const float* __restrict__ X, u16* __restrict__ Y, int n4) {
    int i = blockIdx.x * 256 + threadIdx.x;
    if (i >= n4) return;
    f4 v = __builtin_nontemporal_load((const f4*)&X[(size_t)i * 4]);
    ushort4 o;
    o.x = f2bf(v[0]); o.y = f2bf(v[1]); o.z = f2bf(v[2]); o.w = f2bf(v[3]);
    *(ushort4*)&Y[(size_t)i * 4] = o;
}

// ---------------- CSR gather: z[n] = X[n]*dinv[n]^2 + sum_{e->n} X[src]*w ----------------
// OB: write bf16 (RNE at write == RNE at GEMM staging -> numerically identical)
template <bool OB>
__global__ __launch_bounds__(256) void k_gather(const u16* __restrict__ X,
                                                const int2* __restrict__ pack,
                                                const int* __restrict__ start,
                                                const int* __restrict__ cnt,
                                                void* __restrict__ zout) {
    int node = blockIdx.x * 4 + (threadIdx.x >> 6);
    if (node >= N_NODES) return;
    int lane = threadIdx.x & 63;
    int half = lane >> 5, j = lane & 31;
    int c4 = j * 4;
    float di = rsqrtf((float)(cnt[node] + 1));
    f4 acc = {0.f, 0.f, 0.f, 0.f};
    if (half == 0) {
        float sl = di * di;
        ushort4 u = *(const ushort4*)&X[(size_t)node * DIM_D + c4];
        acc[0] = bf2f(u.x) * sl; acc[1] = bf2f(u.y) * sl;
        acc[2] = bf2f(u.z) * sl; acc[3] = bf2f(u.w) * sl;
    }
    int s0 = start[node], e0 = start[node + 1];
    int h0 = (e0 - s0 + 1) >> 1;
    int i   = half ? (s0 + h0) : s0;
    int end = half ? e0 : (s0 + h0);
    // 4-deep software pipeline: 4 independent pack loads, then 4 row loads in flight
    for (; i + 3 < end; i += 4) {
        i2 p0 = __builtin_nontemporal_load((const i2*)&pack[i]);
        i2 p1 = __builtin_nontemporal_load((const i2*)&pack[i + 1]);
        i2 p2 = __builtin_nontemporal_load((const i2*)&pack[i + 2]);
        i2 p3 = __builtin_nontemporal_load((const i2*)&pack[i + 3]);
        ushort4 u0 = *(const ushort4*)&X[(size_t)p0[0] * DIM_D + c4];
        ushort4 u1 = *(const ushort4*)&X[(size_t)p1[0] * DIM_D + c4];
        ushort4 u2 = *(const ushort4*)&X[(size_t)p2[0] * DIM_D + c4];
        ushort4 u3 = *(const ushort4*)&X[(size_t)p3[0] * DIM_D + c4];
        float w0 = __int_as_float(p0[1]), w1 = __int_as_float(p1[1]);
        float w2 = __int_as_float(p2[1]), w3 = __int_as_float(p3[1]);
        acc[0] += bf2f(u0.x) * w0; acc[1] += bf2f(u0.y) * w0;
        acc[2] += bf2f(u0.z) * w0; acc[3] += bf2f(u0.w) * w0;
        acc[0] += bf2f(u1.x) * w1; acc[1] += bf2f(u1.y) * w1;
        acc[2] += bf2f(u1.z) * w1; acc[3] += bf2f(u1.w) * w1;
        acc[0] += bf2f(u2.x) * w2; acc[1] += bf2f(u2.y) * w2;
        acc[2] += bf2f(u2.z) * w2; acc[3] += bf2f(u2.w) * w2;
        acc[0] += bf2f(u3.x) * w3; acc[1] += bf2f(u3.y) * w3;
        acc[2] += bf2f(u3.z) * w3; acc[3] += bf2f(u3.w) * w3;
    }
    for (; i < end; i++) {
        i2 p = __builtin_nontemporal_load((const i2*)&pack[i]);
        float w = __int_as_float(p[1]);
        ushort4 u = *(const ushort4*)&X[(size_t)p[0] * DIM_D + c4];
        acc[0] += bf2f(u.x) * w; acc[1] += bf2f(u.y) * w;
        acc[2] += bf2f(u.z) * w; acc[3] += bf2f(u.w) * w;
    }
    // combine halves: lane j (<32) += lane j+32
    float t0 = acc[0] + __shfl(acc[0], j + 32);
    float t1 = acc[1] + __shfl(acc[1], j + 32);
    float t2 = acc[2] + __shfl(acc[2], j + 32);
    float t3 = acc[3] + __shfl(acc[3], j + 32);
    if (half == 0) {
        if (OB) {
            s4 o = pk_bf16x4(t0, t1, t2, t3);
            *(s4*)&((u16*)zout)[(size_t)node * DIM_D + c4] = o;
        } else {
            *(float4*)&((float*)zout)[(size_t)node * DIM_D + c4] = make_float4(t0, t1, t2, t3);
        }
    }
}

// ---------------- MFMA GEMM: C[M][Nn] = post(A[M][K] @ W + postB), W given as Wt[Nn][K] bf16 ----
#define BM 128
#define BK 32
#define BKP 56   // padded K stride in LDS (bf16 elems)

template <int BNv, bool A_BF16, bool PRE_BR, bool POST_RELU, bool OUT_BF16, bool PERM_PQ>
__global__ __launch_bounds__(256) void k_gemm(const void* __restrict__ Ap,
                                              const u16* __restrict__ Wt,
                                              const float* __restrict__ preB,
                                              const float* __restrict__ postB,
                                              void* __restrict__ Cp,
                                              int M, int K, int Nn) {
    constexpr int BNT = BNv / 16;            // 16x16 col-tiles per wave row
    __shared__ __align__(16) u16 As[BM * BKP];
    __shared__ __align__(16) u16 Bs[BNv * BKP];
    const int tid = threadIdx.x;
    const int wid = tid >> 6, lane = tid & 63;
    const int q = lane >> 4, l = lane & 15;
    const int bm = blockIdx.x * BM, bn = blockIdx.y * BNv;

    f4 acc[2 * BNT];
#pragma unroll
    for (int i = 0; i < 2 * BNT; i++) { f4 zz = {0.f, 0.f, 0.f, 0.f}; acc[i] = zz; }

    for (int k0 = 0; k0 < K; k0 += BK) {
        __syncthreads();
        // stage W tile: Bs[n][k], n in [bn,bn+BNv), k in [k0,k0+32)
#pragma unroll
        for (int p = 0; p < BNv / 64; p++) {
            int n = (tid >> 2) + p * 64, kc = (tid & 3) * 8;
            *(int4*)&Bs[n * BKP + kc] = *(const int4*)&Wt[(size_t)(bn + n) * K + k0 + kc];
        }
        // stage A tile: As[m][k]
        if (A_BF16) {
            const u16* A = (const u16*)Ap;
#pragma unroll
            for (int p = 0; p < 2; p++) {
                int m = (tid >> 2) + p * 64, kc = (tid & 3) * 8;
                int gm = bm + m; if (gm >= M) gm = M - 1;
                *(int4*)&As[m * BKP + kc] = *(const int4*)&A[(size_t)gm * K + k0 + kc];
            }
        } else {
            const float* A = (const float*)Ap;
#pragma unroll
            for (int p = 0; p < 4; p++) {
                int m = (tid >> 3) + p * 32, k4 = (tid & 7) * 4;
                int gm = bm + m; if (gm >= M) gm = M - 1;
                float4 v = *(const float4*)&A[(size_t)gm * K + k0 + k4];
                if (PRE_BR) {
                    const float4 pb = *(const float4*)&preB[k0 + k4];
                    v.x = fmaxf(v.x + pb.x, 0.f);
                    v.y = fmaxf(v.y + pb.y, 0.f);
                    v.z = fmaxf(v.z + pb.z, 0.f);
                    v.w = fmaxf(v.w + pb.w, 0.f);
                }
                s4 o = pk_bf16x4(v.x, v.y, v.z, v.w);
                *(s4*)&As[m * BKP + k4] = o;
            }
        }
        __syncthreads();

        s8 af[2], bf[BNT];
#pragma unroll
        for (int mt = 0; mt < 2; mt++)
            af[mt] = *(const s8*)&As[(wid * 32 + mt * 16 + l) * BKP + q * 8];
#pragma unroll
        for (int nt = 0; nt < BNT; nt++)
            bf[nt] = *(const s8*)&Bs[(nt * 16 + l) * BKP + q * 8];
#pragma unroll
        for (int mt = 0; mt < 2; mt++)
#pragma unroll
            for (int nt = 0; nt < BNT; nt++)
                acc[mt * BNT + nt] = __builtin_amdgcn_mfma_f32_16x16x32_bf16(
                    af[mt], bf[nt], acc[mt * BNT + nt], 0, 0, 0);
    }

    // epilogue: C row = q*4+r, col = l (per 16x16 tile)
#pragma unroll
    for (int mt = 0; mt < 2; mt++) {
#pragma unroll
        for (int nt = 0; nt < BNT; nt++) {
            int colg = bn + nt * 16 + l;                // logical col (bias index)
            float pb = postB ? postB[colg] : 0.0f;
            int cols = colg;
            if (PERM_PQ) {
                int w = colg & 63, mtL = w >> 4;
                cols = (colg & ~63) | (((mtL >> 1) & 1) * 32) | (((w >> 2) & 3) * 8)
                       | ((mtL & 1) * 4) | (w & 3);
            }
#pragma unroll
            for (int r = 0; r < 4; r++) {
                int rowg = bm + wid * 32 + mt * 16 + q * 4 + r;
                if (rowg < M) {
                    float v = acc[mt * BNT + nt][r] + pb;
                    if (POST_RELU) v = fmaxf(v, 0.f);
                    if (OUT_BF16)
                        ((u16*)Cp)[(size_t)rowg * Nn + cols] = f2bf_hw(v);
                    else
                        ((float*)Cp)[(size_t)rowg * Nn + cols] = v;
                }
            }
        }
    }
}

// ---------------- edge predictor: 16 edges (CSR slots) per wave -----------------------------
// v8 = v7 (frozen logic) + non-temporal hints on streaming data (attr/out/pack/eidx) so the
// 51 MB PQ table stays L3-resident (round-7 FETCH=252MB >> resident set => L3 thrash).
#if __has_builtin(__builtin_amdgcn_mfma_f32_16x16x16bf16_1k)
#define KEEP4(a,b,c,d) asm volatile("" :: "v"(a), "v"(b), "v"(c), "v"(d))
__global__ __launch_bounds__(256) void k_edge(const u16* __restrict__ PQ,     // [N][512]: P|Q (permuted)
                                              const float* __restrict__ attr,
                                              const int2* __restrict__ pack,
                                              const int2* __restrict__ eidx,
                                              const u16* __restrict__ Wct,    // [256][16] bf16
                                              const u16* __restrict__ We2t,   // [16][256] bf16
                                              const float* __restrict__ be2,
                                              float* __restrict__ outp) {
    // interleaved weight table: [mt][lane=q*16+l] x {wc frag (4 u16), we frag (4 u16)} = 16 KB
    __shared__ __align__(16) u16 lw[16 * 64 * 8];
    const int tid = threadIdx.x, wid = tid >> 6, lane = tid & 63;
    const int q = lane >> 4, l = lane & 15;
    for (int u = tid; u < 1024; u += 256) {
        int smt = u >> 6, sq = (u >> 4) & 3, sl = u & 15;
        *(uint2*)&lw[u * 8]     = *(const uint2*)&Wct[(smt * 16 + sl) * 16 + sq * 4];
        *(uint2*)&lw[u * 8 + 4] = *(const uint2*)&We2t[sl * DIM_H + smt * 16 + sq * 4];
    }
    __syncthreads();

    const float4 be2v = *(const float4*)&be2[q * 4];
    const int NT = N_EDGES / 16;
    const int step = gridDim.x * 4;
    const int lbase = lane * 8;           // lds elem offset of this lane's frag pair (per mt: +512)

    int tile = blockIdx.x * 4 + wid;
    if (tile >= NT) return;
    i2 pk = __builtin_nontemporal_load((const i2*)&pack[tile * 16 + l]);   // {src, weight(unused)}
    i2 ec = __builtin_nontemporal_load((const i2*)&eidx[tile * 16 + l]);   // {orig edge, dst}

    for (; tile < NT; tile += step) {
        const int re = pk[0], e = ec[0], ce = ec[1];
        const u16* prow = PQ + (size_t)re * 512 + q * 8;          // P half (random, LLC)
        const u16* qrow = PQ + (size_t)ce * 512 + 256 + q * 8;    // Q half (CSR runs, L1)

        // issue the whole gather batch: attr + 16 wide P/Q loads (16B/lane, 64B/edge/instr)
        f4 av = __builtin_nontemporal_load((const f4*)&attr[(size_t)e * DIM_A + q * 4]);
        s8 pw[8], qw[8];
#pragma unroll
        for (int w = 0; w < 8; w++) {
            pw[w] = *(const s8*)(prow + w * 32);
            qw[w] = *(const s8*)(qrow + w * 32);
        }
        // prefetch next tile's indices (independent of current compute)
        int ntile = tile + step;
        int ns = (ntile < NT) ? ntile * 16 + l : l;
        i2 pk_n = __builtin_nontemporal_load((const i2*)&pack[ns]);
        i2 ec_n = __builtin_nontemporal_load((const i2*)&eidx[ns]);
        // pin: force all batch results live here (IR sinking cannot cross asm operands)
        KEEP4(pw[0], pw[1], pw[2], pw[3]);
        KEEP4(pw[4], pw[5], pw[6], pw[7]);
        KEEP4(qw[0], qw[1], qw[2], qw[3]);
        KEEP4(qw[4], qw[5], qw[6], qw[7]);
        __builtin_amdgcn_sched_barrier(0);

        s4 af = pk_bf16x4(av[0], av[1], av[2], av[3]);   // attr B-frag: B[k=q*4+j][n=edge=l]

        f4 acc2 = {0.f, 0.f, 0.f, 0.f};
#pragma unroll
        for (int w = 0; w < 8; w++) {
#pragma unroll
            for (int s = 0; s < 2; s++) {
                const int mt = w * 2 + s;
                s8 wf = *(const s8*)&lw[mt * 512 + lbase];
                s4 wcf = {wf[0], wf[1], wf[2], wf[3]};
                s4 wef = {wf[4], wf[5], wf[6], wf[7]};
                // C-in = P+Q (layout: reg j <-> row q*4+j, col l — matches D exactly)
                f4 pqs;
                pqs[0] = bf2f((u16)pw[w][s * 4 + 0]) + bf2f((u16)qw[w][s * 4 + 0]);
                pqs[1] = bf2f((u16)pw[w][s * 4 + 1]) + bf2f((u16)qw[w][s * 4 + 1]);
                pqs[2] = bf2f((u16)pw[w][s * 4 + 2]) + bf2f((u16)qw[w][s * 4 + 2]);
                pqs[3] = bf2f((u16)pw[w][s * 4 + 3]) + bf2f((u16)qw[w][s * 4 + 3]);
                f4 acc = __builtin_amdgcn_mfma_f32_16x16x16bf16_1k(wcf, af, pqs, 0, 0, 0);
                s4 uf = pk_bf16x4(fmaxf(acc[0], 0.f), fmaxf(acc[1], 0.f),
                                  fmaxf(acc[2], 0.f), fmaxf(acc[3], 0.f));
                acc2 = __builtin_amdgcn_mfma_f32_16x16x16bf16_1k(wef, uf, acc2, 0, 0, 0);
            }
        }
        // D: col=edge l, row=outcol q*4+r -> one 64B nt store per edge row (scatter via e)
        f4 ov = {acc2[0] + be2v.x, acc2[1] + be2v.y, acc2[2] + be2v.z, acc2[3] + be2v.w};
        __builtin_nontemporal_store(ov, (f4*)&outp[(size_t)e * DIM_A + q * 4]);
        pk = pk_n; ec = ec_n;
    }
}
#else
// Fallback (x32 MFMA + per-wave LDS round-trip), operand-swapped MFMA-2 + float4 store.
#define UPAD 268
__global__ __launch_bounds__(256) void k_edge(const u16* __restrict__ PQ,
                                              const float* __restrict__ attr,
                                              const int2* __restrict__ pack,
                                              const int2* __restrict__ eidx,
                                              const u16* __restrict__ Wct,
                                              const u16* __restrict__ We2t,
                                              const float* __restrict__ be2,
                                              float* __restrict__ outp) {
    __shared__ __align__(16) u16 ub[4][16][UPAD];
    const int tid = threadIdx.x, wid = tid >> 6, lane = tid & 63;
    const int q = lane >> 4, l = lane & 15;
    const float4 be2v = *(const float4*)&be2[q * 4];
    u16(*u)[UPAD] = ub[wid];

    s8 wcf[16];
#pragma unroll
    for (int mt = 0; mt < 16; mt++) {
        wcf[mt] = zero_s8();
        if (q < 2) wcf[mt] = *(const s8*)&Wct[(mt * 16 + l) * 16 + q * 8];
    }

    for (int tile = blockIdx.x * 4 + wid; tile < N_EDGES / 16; tile += gridDim.x * 4) {
        const int s = tile * 16 + l;
        const int2 pk = pack[s];
        const int2 ec = eidx[s];
        const int re = pk.x, e = ec.x, ce = ec.y;
        const u16* prow = PQ + (size_t)re * 512;
        const u16* qrow = PQ + (size_t)ce * 512 + 256;

        s8 af = zero_s8();
        if (q < 2) {
            const float* ap = &attr[(size_t)e * DIM_A + q * 8];
            float4 a0 = *(const float4*)ap;
            float4 a1 = *(const float4*)(ap + 4);
            af[0] = (short)f2bf(a0.x); af[1] = (short)f2bf(a0.y);
            af[2] = (short)f2bf(a0.z); af[3] = (short)f2bf(a0.w);
            af[4] = (short)f2bf(a1.x); af[5] = (short)f2bf(a1.y);
            af[6] = (short)f2bf(a1.z); af[7] = (short)f2bf(a1.w);
        }

#pragma unroll
        for (int mt = 0; mt < 16; mt++) {
            f4 cz = {0.f, 0.f, 0.f, 0.f};
            f4 acc = __builtin_amdgcn_mfma_f32_16x16x32_bf16(wcf[mt], af, cz, 0, 0, 0);
            ushort4 pu = *(const ushort4*)(prow + pq_off(mt, q));
            ushort4 qu = *(const ushort4*)(qrow + pq_off(mt, q));
            float t0 = bf2f(pu.x) + bf2f(qu.x) + acc[0];
            float t1 = bf2f(pu.y) + bf2f(qu.y) + acc[1];
            float t2 = bf2f(pu.z) + bf2f(qu.z) + acc[2];
            float t3 = bf2f(pu.w) + bf2f(qu.w) + acc[3];
            ushort4 o;
            o.x = f2bf(fmaxf(t0, 0.f)); o.y = f2bf(fmaxf(t1, 0.f));
            o.z = f2bf(fmaxf(t2, 0.f)); o.w = f2bf(fmaxf(t3, 0.f));
            *(ushort4*)&u[l][mt * 16 + q * 4] = o;
        }

        f4 acc2 = {0.f, 0.f, 0.f, 0.f};
#pragma unroll
        for (int ks = 0; ks < 8; ks++) {
            s8 uf = *(const s8*)&u[l][ks * 32 + q * 8];
            s8 wf = *(const s8*)&We2t[(size_t)l * DIM_H + ks * 32 + q * 8];
            acc2 = __builtin_amdgcn_mfma_f32_16x16x32_bf16(wf, uf, acc2, 0, 0, 0);
        }
        *(float4*)&outp[(size_t)e * DIM_A + q * 4] =
            make_float4(acc2[0] + be2v.x, acc2[1] + be2v.y,
                        acc2[2] + be2v.z, acc2[3] + be2v.w);
    }
}
#endif

extern "C" void kernel_launch(void* const* d_in, const int* in_sizes, int n_in,
                              void* d_out, int out_size, void* d_ws, size_t ws_size,
                              hipStream_t stream) {
    (void)in_sizes; (void)n_in; (void)out_size; (void)ws_size;
    const float* x    = (const float*)d_in[0];
    const int*   ei   = (const int*)d_in[1];
    const float* attr = (const float*)d_in[2];
    const float* W1   = (const float*)d_in[3];
    const float* b1   = (const float*)d_in[4];
    const float* W2   = (const float*)d_in[5];
    const float* b2   = (const float*)d_in[6];
    const float* Wo1  = (const float*)d_in[7];
    const float* bo1  = (const float*)d_in[8];
    const float* Wo2  = (const float*)d_in[9];
    const float* bo2  = (const float*)d_in[10];
    const float* We1  = (const float*)d_in[11];
    const float* be1  = (const float*)d_in[12];
    const float* We2  = (const float*)d_in[13];
    const float* be2  = (const float*)d_in[14];
    const int* rowi = ei;
    const int* coli = ei + N_EDGES;

    float* hout = (float*)d_out;                       // [N][128]
    float* eout = hout + (size_t)N_NODES * DIM_D;      // [E][16]

    char* ws = (char*)d_ws;
    size_t off = 0;
    auto nxt = [&](size_t b) -> void* {
        void* p = ws + off; off = (off + b + 255) & ~(size_t)255; return p;
    };
    int* cnt    = (int*)nxt((size_t)N_NODES * 4);
    int* startp = (int*)nxt((size_t)(N_NODES + 1) * 4);
    int* cursor = (int*)nxt((size_t)N_NODES * 4);
    int2* pack  = (int2*)nxt((size_t)N_EDGES * 8);
    int2* eidx  = (int2*)nxt((size_t)N_EDGES * 8);
    u16* W1t   = (u16*)nxt(128 * 256 * 2);
    u16* W2t   = (u16*)nxt(128 * 256 * 2);
    u16* Wo1t  = (u16*)nxt(128 * 256 * 2);
    u16* Wo2t  = (u16*)nxt(128 * 256 * 2);
    u16* Wabt  = (u16*)nxt(512 * 128 * 2);   // [512][128]: Wa^T | Wb^T
    u16* Wct   = (u16*)nxt(256 * 16 * 2);
    u16* We2t  = (u16*)nxt(16 * 256 * 2);
    float* bpq = (float*)nxt(512 * 4);
    u16* xb    = (u16*)nxt((size_t)N_NODES * DIM_D * 2);     // x cast to bf16
    float* z   = (float*)nxt((size_t)N_NODES * DIM_D * 4);   // Ây accumulator (fp32); layer-1 z (bf16) overlays it
    u16* h1    = (u16*)nxt((size_t)N_NODES * DIM_H * 2);     // intermediate [N][256]
    u16* yb    = (u16*)nxt((size_t)N_NODES * DIM_D * 2);
    // PQ [N][512] bf16 (51.2 MB) overlays z+h1 (both dead once hout is computed)
    u16* PQb = (u16*)z;
    u16* zb  = (u16*)z;    // layer-1 gather output (bf16, 12.8 MB) — dead before gather-2 rewrites z

    const int gE = (N_EDGES + 255) / 256;

    // fused init: all weight transposes + bpq + cnt=0  (was 11 launches)
    k_init<<<(205312 + N_NODES + 255) / 256, 256, 0, stream>>>(
        W1, W2, Wo1, Wo2, We1, We2, be1,
        W1t, W2t, Wo1t, Wo2t, Wabt, Wct, We2t, bpq, cnt);

    // ---- CSR build ----
    k_count<<<gE, 256, 0, stream>>>(coli, cnt);
    k_scan<<<1, 1024, 0, stream>>>(cnt, startp, cursor);
    k_fill<<<gE, 256, 0, stream>>>(rowi, coli, cnt, cursor, pack, eidx);

    // cast x -> bf16 (halves layer-1 gather traffic)
    k_cast<<<(N_NODES * DIM_D / 4 + 255) / 256, 256, 0, stream>>>(x, xb, N_NODES * DIM_D / 4);

    const int gG = (N_NODES + 3) / 4;   // 4 nodes (waves) per block
    // layer 1: zb = Âx (bf16) ; h1 = relu(zb@W1 + b1)   [BN=128]
    k_gather<true><<<gG, 256, 0, stream>>>(xb, pack, startp, cnt, zb);
    k_gemm<128, true, false, true, true, false><<<dim3(391, 2), 256, 0, stream>>>(zb, W1t, nullptr, b1, h1, N_NODES, 128, 256);
    // layer 2: y = h1@W2 ; z = Ây (fp32) ; h2 = relu(z + b2) fused into next GEMM's A-stage
    k_gemm<64, true, false, false, true, false><<<dim3(391, 2), 256, 0, stream>>>(h1, W2t, nullptr, nullptr, yb, N_NODES, 256, 128);
    k_gather<false><<<gG, 256, 0, stream>>>(yb, pack, startp, cnt, z);
    // output MLP: h3 = relu(relu(z+b2)@Wo1 + bo1) ; h = h3@Wo2 + bo2 -> d_out (fp32)
    k_gemm<128, false, true, true, true, false><<<dim3(391, 2), 256, 0, stream>>>(z, Wo1t, b2, bo1, h1, N_NODES, 128, 256);
    k_gemm<64, true, false, false, false, false><<<dim3(391, 2), 256, 0, stream>>>(h1, Wo2t, nullptr, bo2, hout, N_NODES, 256, 128);
    // edge predictor precompute: PQ = [h@Wa + be1 | h@Wb]  (bf16, [N][512], permuted cols)
    k_gemm<128, false, false, false, true, true><<<dim3(391, 4), 256, 0, stream>>>(hout, Wabt, nullptr, bpq, PQb, N_NODES, 128, 512);
    // per-edge (CSR slot order): out = relu(P[src]+Q[dst]+attr@Wc)@We2 + be2
    k_edge<<<2048, 256, 0, stream>>>(PQb, attr, pack, eidx, Wct, We2t, be2, eout);
}

// Round 9
// 568.424 us; speedup vs baseline: 1.1943x; 1.1943x over previous
//
#include <hip/hip_runtime.h>
#include <hip/hip_bf16.h>

// Problem constants (from reference): N=50000, E=800000, D=128, H=256, A=16
#define N_NODES 50000
#define N_EDGES 800000
#define DIM_D   128
#define DIM_H   256
#define DIM_A   16

typedef unsigned short u16;
typedef __attribute__((ext_vector_type(4))) float f4;
typedef __attribute__((ext_vector_type(8))) short s8;
typedef __attribute__((ext_vector_type(4))) short s4;
typedef __attribute__((ext_vector_type(2))) int i2;

__device__ __forceinline__ u16 f2bf(float f) {
    union { float f; unsigned u; } v; v.f = f;
    unsigned r = v.u + 0x7FFFu + ((v.u >> 16) & 1u);   // RNE
    return (u16)(r >> 16);
}
__device__ __forceinline__ float bf2f(u16 s) {
    union { unsigned u; float f; } v; v.u = ((unsigned)s) << 16; return v.f;
}
__device__ __forceinline__ s8 zero_s8() {
    s8 v;
#pragma unroll
    for (int i = 0; i < 8; i++) v[i] = 0;
    return v;
}
// HW-packed f32->bf16 via HIP intrinsics (compiler emits v_cvt_pk_bf16_f32; RNE, no inline asm)
__device__ __forceinline__ s4 pk_bf16x4(float a, float b, float c, float d) {
    __hip_bfloat162 h0 = __float22bfloat162_rn(make_float2(a, b));
    __hip_bfloat162 h1 = __float22bfloat162_rn(make_float2(c, d));
    s4 v;
    __builtin_memcpy(&v, &h0, 4);
    __builtin_memcpy(((char*)&v) + 4, &h1, 4);
    return v;
}
__device__ __forceinline__ u16 f2bf_hw(float f) {
    __hip_bfloat16 h = __float2bfloat16(f);
    u16 u; __builtin_memcpy(&u, &h, 2);
    return u;
}

// ---- PQ permuted column layout (within each 64-col group of a PQ row) ----
// stored[i*32 + q*8 + s*4 + j] = logical[(2i+s)*16 + q*4 + j]
__device__ __forceinline__ int pq_off(int mt, int q) {   // stored elem offset of logical chunk (mt, q)
    return (mt >> 2) * 64 + ((mt >> 1) & 1) * 32 + q * 8 + (mt & 1) * 4;
}

// ---------------- fused init: 8 weight transposes + bpq + cnt zero ----------------
__global__ __launch_bounds__(256) void k_init(const float* __restrict__ W1, const float* __restrict__ W2,
                                              const float* __restrict__ Wo1, const float* __restrict__ Wo2,
                                              const float* __restrict__ We1, const float* __restrict__ We2,
                                              const float* __restrict__ be1,
                                              u16* __restrict__ W1t, u16* __restrict__ W2t,
                                              u16* __restrict__ Wo1t, u16* __restrict__ Wo2t,
                                              u16* __restrict__ Wabt, u16* __restrict__ Wct,
                                              u16* __restrict__ We2t, float* __restrict__ bpq,
                                              int* __restrict__ cnt) {
    int idx = blockIdx.x * 256 + threadIdx.x;
    if (idx < 32768) {                 // W1 [128][256] -> W1t [256][128]
        int k = idx >> 8, n = idx & 255;
        W1t[n * 128 + k] = f2bf(W1[idx]);
    } else if (idx < 65536) {          // W2 [256][128] -> W2t [128][256]
        int r = idx - 32768, k = r >> 7, n = r & 127;
        W2t[n * 256 + k] = f2bf(W2[r]);
    } else if (idx < 98304) {          // Wo1 [128][256] -> Wo1t [256][128]
        int r = idx - 65536, k = r >> 8, n = r & 255;
        Wo1t[n * 128 + k] = f2bf(Wo1[r]);
    } else if (idx < 131072) {         // Wo2 [256][128] -> Wo2t [128][256]
        int r = idx - 98304, k = r >> 7, n = r & 127;
        Wo2t[n * 256 + k] = f2bf(Wo2[r]);
    } else if (idx < 163840) {         // Wa = We1 rows 0..127 -> Wabt[0..]
        int r = idx - 131072, k = r >> 8, n = r & 255;
        Wabt[n * 128 + k] = f2bf(We1[r]);
    } else if (idx < 196608) {         // Wb = We1 rows 128..255 -> Wabt[32768..]
        int r = idx - 163840, k = r >> 8, n = r & 255;
        Wabt[32768 + n * 128 + k] = f2bf(We1[32768 + r]);
    } else if (idx < 200704) {         // Wc = We1 rows 256..271 [16][256] -> Wct [256][16]
        int r = idx - 196608, k = r >> 8, n = r & 255;
        Wct[n * 16 + k] = f2bf(We1[65536 + r]);
    } else if (idx < 204800) {         // We2 [256][16] -> We2t [16][256]
        int r = idx - 200704, k = r >> 4, n = r & 15;
        We2t[n * 256 + k] = f2bf(We2[r]);
    } else if (idx < 205312) {         // bpq
        int i = idx - 204800;
        bpq[i] = (i < 256) ? be1[i] : 0.f;
    } else if (idx < 205312 + N_NODES) {
        cnt[idx - 205312] = 0;
    }
}

// ---------------- CSR build ----------------
__global__ __launch_bounds__(256) void k_count(const int* __restrict__ coli, int* __restrict__ cnt) {
    int e = blockIdx.x * 256 + threadIdx.x;
    if (e < N_EDGES) atomicAdd(&cnt[__builtin_nontemporal_load(&coli[e])], 1);
}

// ---- hierarchical scan (round-8 PMC: single-block k_scan was 125 µs, the largest dispatch —
//      one CU, uncoalesced 196B-stride stores; 3-phase version is coalesced + all-CU) ----
#define SCAN_BLOCKS 196   // 196*256 = 50176 >= N_NODES

// phase 1: per-block exclusive prefix into start[], block total into bsum[]
__global__ __launch_bounds__(256) void k_scan1(const int* __restrict__ cnt, int* __restrict__ start,
                                               int* __restrict__ bsum) {
    __shared__ int ps[256];
    int t = threadIdx.x, idx = blockIdx.x * 256 + t;
    int v = (idx < N_NODES) ? cnt[idx] : 0;
    ps[t] = v;
    __syncthreads();
    for (int ofs = 1; ofs < 256; ofs <<= 1) {
        int u = (t >= ofs) ? ps[t - ofs] : 0;
        __syncthreads();
        ps[t] += u;
        __syncthreads();
    }
    if (idx < N_NODES) start[idx] = ps[t] - v;     // local exclusive
    if (t == 255) bsum[blockIdx.x] = ps[255];
}
// phase 2: scan block sums -> boff[]; write start[N_NODES] = total
__global__ __launch_bounds__(256) void k_scan2(const int* __restrict__ bsum, int* __restrict__ boff,
                                               int* __restrict__ start) {
    __shared__ int ps[256];
    int t = threadIdx.x;
    int v = (t < SCAN_BLOCKS) ? bsum[t] : 0;
    ps[t] = v;
    __syncthreads();
    for (int ofs = 1; ofs < 256; ofs <<= 1) {
        int u = (t >= ofs) ? ps[t - ofs] : 0;
        __syncthreads();
        ps[t] += u;
        __syncthreads();
    }
    if (t < SCAN_BLOCKS) boff[t] = ps[t] - v;
    if (t == 255) start[N_NODES] = ps[255];
}
// phase 3: add block offset; mirror into cursor
__global__ __launch_bounds__(256) void k_scan3(int* __restrict__ start, const int* __restrict__ boff,
                                               int* __restrict__ cursor) {
    int idx = blockIdx.x * 256 + threadIdx.x;
    if (idx >= N_NODES) return;
    int s = start[idx] + boff[blockIdx.x];
    start[idx] = s;
    cursor[idx] = s;
}

// pack[slot] = {src_node, dinv[src]*dinv[dst]} bucketed by destination (dinv from cnt inline)
// eidx[slot] = {orig_edge, dst_node} (for CSR-ordered edge predictor)
__global__ __launch_bounds__(256) void k_fill(const int* __restrict__ rowi, const int* __restrict__ coli,
                                              const int* __restrict__ cnt,
                                              int* __restrict__ cursor, int2* __restrict__ pack,
                                              int2* __restrict__ eidx) {
    int e = blockIdx.x * 256 + threadIdx.x;
    if (e >= N_EDGES) return;
    int r = __builtin_nontemporal_load(&rowi[e]);
    int c = __builtin_nontemporal_load(&coli[e]);
    int slot = atomicAdd(&cursor[c], 1);
    float w = rsqrtf((float)(cnt[r] + 1)) * rsqrtf((float)(cnt[c] + 1));
    pack[slot] = make_int2(r, __float_as_int(w));
    eidx[slot] = make_int2(e, c);
}

// ---------------- fp32 -> bf16 cast (x table) ----------------
__global__ __launch_bounds__(256) void k_cast(const float* __restrict__ X, u16* __restrict__ Y, int n4) {
    int i = blockIdx.x * 256 + threadIdx.x;
    if (i >= n4) return;
    f4 v = __builtin_nontemporal_load((const f4*)&X[(size_t)i * 4]);
    ushort4 o;
    o.x = f2bf(v[0]); o.y = f2bf(v[1]); o.z = f2bf(v[2]); o.w = f2bf(v[3]);
    *(ushort4*)&Y[(size_t)i * 4] = o;
}

// ---------------- CSR gather: z[n] = X[n]*dinv[n]^2 + sum_{e->n} X[src]*w ----------------
// OB: write bf16 (RNE at write == RNE at GEMM staging -> numerically identical)
template <bool OB>
__global__ __launch_bounds__(256) void k_gather(const u16* __restrict__ X,
                                                const int2* __restrict__ pack,
                                                const int* __restrict__ start,
                                                const int* __restrict__ cnt,
                                                void* __restrict__ zout) {
    int node = blockIdx.x * 4 + (threadIdx.x >> 6);
    if (node >= N_NODES) return;
    int lane = threadIdx.x & 63;
    int half = lane >> 5, j = lane & 31;
    int c4 = j * 4;
    float di = rsqrtf((float)(cnt[node] + 1));
    f4 acc = {0.f, 0.f, 0.f, 0.f};
    if (half == 0) {
        float sl = di * di;
        ushort4 u = *(const ushort4*)&X[(size_t)node * DIM_D + c4];
        acc[0] = bf2f(u.x) * sl; acc[1] = bf2f(u.y) * sl;
        acc[2] = bf2f(u.z) * sl; acc[3] = bf2f(u.w) * sl;
    }
    int s0 = start[node], e0 = start[node + 1];
    int h0 = (e0 - s0 + 1) >> 1;
    int i   = half ? (s0 + h0) : s0;
    int end = half ? e0 : (s0 + h0);
    // 4-deep software pipeline: 4 independent pack loads, then 4 row loads in flight
    for (; i + 3 < end; i += 4) {
        i2 p0 = __builtin_nontemporal_load((const i2*)&pack[i]);
        i2 p1 = __builtin_nontemporal_load((const i2*)&pack[i + 1]);
        i2 p2 = __builtin_nontemporal_load((const i2*)&pack[i + 2]);
        i2 p3 = __builtin_nontemporal_load((const i2*)&pack[i + 3]);
        ushort4 u0 = *(const ushort4*)&X[(size_t)p0[0] * DIM_D + c4];
        ushort4 u1 = *(const ushort4*)&X[(size_t)p1[0] * DIM_D + c4];
        ushort4 u2 = *(const ushort4*)&X[(size_t)p2[0] * DIM_D + c4];
        ushort4 u3 = *(const ushort4*)&X[(size_t)p3[0] * DIM_D + c4];
        float w0 = __int_as_float(p0[1]), w1 = __int_as_float(p1[1]);
        float w2 = __int_as_float(p2[1]), w3 = __int_as_float(p3[1]);
        acc[0] += bf2f(u0.x) * w0; acc[1] += bf2f(u0.y) * w0;
        acc[2] += bf2f(u0.z) * w0; acc[3] += bf2f(u0.w) * w0;
        acc[0] += bf2f(u1.x) * w1; acc[1] += bf2f(u1.y) * w1;
        acc[2] += bf2f(u1.z) * w1; acc[3] += bf2f(u1.w) * w1;
        acc[0] += bf2f(u2.x) * w2; acc[1] += bf2f(u2.y) * w2;
        acc[2] += bf2f(u2.z) * w2; acc[3] += bf2f(u2.w) * w2;
        acc[0] += bf2f(u3.x) * w3; acc[1] += bf2f(u3.y) * w3;
        acc[2] += bf2f(u3.z) * w3; acc[3] += bf2f(u3.w) * w3;
    }
    for (; i < end; i++) {
        i2 p = __builtin_nontemporal_load((const i2*)&pack[i]);
        float w = __int_as_float(p[1]);
        ushort4 u = *(const ushort4*)&X[(size_t)p[0] * DIM_D + c4];
        acc[0] += bf2f(u.x) * w; acc[1] += bf2f(u.y) * w;
        acc[2] += bf2f(u.z) * w; acc[3] += bf2f(u.w) * w;
    }
    // combine halves: lane j (<32) += lane j+32
    float t0 = acc[0] + __shfl(acc[0], j + 32);
    float t1 = acc[1] + __shfl(acc[1], j + 32);
    float t2 = acc[2] + __shfl(acc[2], j + 32);
    float t3 = acc[3] + __shfl(acc[3], j + 32);
    if (half == 0) {
        if (OB) {
            s4 o = pk_bf16x4(t0, t1, t2, t3);
            *(s4*)&((u16*)zout)[(size_t)node * DIM_D + c4] = o;
        } else {
            *(float4*)&((float*)zout)[(size_t)node * DIM_D + c4] = make_float4(t0, t1, t2, t3);
        }
    }
}

// ---------------- MFMA GEMM: C[M][Nn] = post(A[M][K] @ W + postB), W given as Wt[Nn][K] bf16 ----
#define BM 128
#define BK 32
#define BKP 56   // padded K stride in LDS (bf16 elems)

template <int BNv, bool A_BF16, bool PRE_BR, bool POST_RELU, bool OUT_BF16, bool PERM_PQ>
__global__ __launch_bounds__(256) void k_gemm(const void* __restrict__ Ap,
                                              const u16* __restrict__ Wt,
                                              const float* __restrict__ preB,
                                              const float* __restrict__ postB,
                                              void* __restrict__ Cp,
                                              int M, int K, int Nn) {
    constexpr int BNT = BNv / 16;            // 16x16 col-tiles per wave row
    __shared__ __align__(16) u16 As[BM * BKP];
    __shared__ __align__(16) u16 Bs[BNv * BKP];
    const int tid = threadIdx.x;
    const int wid = tid >> 6, lane = tid & 63;
    const int q = lane >> 4, l = lane & 15;
    const int bm = blockIdx.x * BM, bn = blockIdx.y * BNv;

    f4 acc[2 * BNT];
#pragma unroll
    for (int i = 0; i < 2 * BNT; i++) { f4 zz = {0.f, 0.f, 0.f, 0.f}; acc[i] = zz; }

    for (int k0 = 0; k0 < K; k0 += BK) {
        __syncthreads();
        // stage W tile: Bs[n][k], n in [bn,bn+BNv), k in [k0,k0+32)
#pragma unroll
        for (int p = 0; p < BNv / 64; p++) {
            int n = (tid >> 2) + p * 64, kc = (tid & 3) * 8;
            *(int4*)&Bs[n * BKP + kc] = *(const int4*)&Wt[(size_t)(bn + n) * K + k0 + kc];
        }
        // stage A tile: As[m][k]
        if (A_BF16) {
            const u16* A = (const u16*)Ap;
#pragma unroll
            for (int p = 0; p < 2; p++) {
                int m = (tid >> 2) + p * 64, kc = (tid & 3) * 8;
                int gm = bm + m; if (gm >= M) gm = M - 1;
                *(int4*)&As[m * BKP + kc] = *(const int4*)&A[(size_t)gm * K + k0 + kc];
            }
        } else {
            const float* A = (const float*)Ap;
#pragma unroll
            for (int p = 0; p < 4; p++) {
                int m = (tid >> 3) + p * 32, k4 = (tid & 7) * 4;
                int gm = bm + m; if (gm >= M) gm = M - 1;
                float4 v = *(const float4*)&A[(size_t)gm * K + k0 + k4];
                if (PRE_BR) {
                    const float4 pb = *(const float4*)&preB[k0 + k4];
                    v.x = fmaxf(v.x + pb.x, 0.f);
                    v.y = fmaxf(v.y + pb.y, 0.f);
                    v.z = fmaxf(v.z + pb.z, 0.f);
                    v.w = fmaxf(v.w + pb.w, 0.f);
                }
                s4 o = pk_bf16x4(v.x, v.y, v.z, v.w);
                *(s4*)&As[m * BKP + k4] = o;
            }
        }
        __syncthreads();

        s8 af[2], bf[BNT];
#pragma unroll
        for (int mt = 0; mt < 2; mt++)
            af[mt] = *(const s8*)&As[(wid * 32 + mt * 16 + l) * BKP + q * 8];
#pragma unroll
        for (int nt = 0; nt < BNT; nt++)
            bf[nt] = *(const s8*)&Bs[(nt * 16 + l) * BKP + q * 8];
#pragma unroll
        for (int mt = 0; mt < 2; mt++)
#pragma unroll
            for (int nt = 0; nt < BNT; nt++)
                acc[mt * BNT + nt] = __builtin_amdgcn_mfma_f32_16x16x32_bf16(
                    af[mt], bf[nt], acc[mt * BNT + nt], 0, 0, 0);
    }

    // epilogue: C row = q*4+r, col = l (per 16x16 tile)
#pragma unroll
    for (int mt = 0; mt < 2; mt++) {
#pragma unroll
        for (int nt = 0; nt < BNT; nt++) {
            int colg = bn + nt * 16 + l;                // logical col (bias index)
            float pb = postB ? postB[colg] : 0.0f;
            int cols = colg;
            if (PERM_PQ) {
                int w = colg & 63, mtL = w >> 4;
                cols = (colg & ~63) | (((mtL >> 1) & 1) * 32) | (((w >> 2) & 3) * 8)
                       | ((mtL & 1) * 4) | (w & 3);
            }
#pragma unroll
            for (int r = 0; r < 4; r++) {
                int rowg = bm + wid * 32 + mt * 16 + q * 4 + r;
                if (rowg < M) {
                    float v = acc[mt * BNT + nt][r] + pb;
                    if (POST_RELU) v = fmaxf(v, 0.f);
                    if (OUT_BF16)
                        ((u16*)Cp)[(size_t)rowg * Nn + cols] = f2bf_hw(v);
                    else
                        ((float*)Cp)[(size_t)rowg * Nn + cols] = v;
                }
            }
        }
    }
}

// ---------------- edge predictor: 16 edges (CSR slots) per wave -----------------------------
// FROZEN (v8): lane-major LDS weight table, permuted wide PQ loads + KEEP4 pin + index
// prefetch, P+Q folded into MFMA-1 C operand, nt hints on streaming data.
#if __has_builtin(__builtin_amdgcn_mfma_f32_16x16x16bf16_1k)
#define KEEP4(a,b,c,d) asm volatile("" :: "v"(a), "v"(b), "v"(c), "v"(d))
__global__ __launch_bounds__(256) void k_edge(const u16* __restrict__ PQ,     // [N][512]: P|Q (permuted)
                                              const float* __restrict__ attr,
                                              const int2* __restrict__ pack,
                                              const int2* __restrict__ eidx,
                                              const u16* __restrict__ Wct,    // [256][16] bf16
                                              const u16* __restrict__ We2t,   // [16][256] bf16
                                              const float* __restrict__ be2,
                                              float* __restrict__ outp) {
    // interleaved weight table: [mt][lane=q*16+l] x {wc frag (4 u16), we frag (4 u16)} = 16 KB
    __shared__ __align__(16) u16 lw[16 * 64 * 8];
    const int tid = threadIdx.x, wid = tid >> 6, lane = tid & 63;
    const int q = lane >> 4, l = lane & 15;
    for (int u = tid; u < 1024; u += 256) {
        int smt = u >> 6, sq = (u >> 4) & 3, sl = u & 15;
        *(uint2*)&lw[u * 8]     = *(const uint2*)&Wct[(smt * 16 + sl) * 16 + sq * 4];
        *(uint2*)&lw[u * 8 + 4] = *(const uint2*)&We2t[sl * DIM_H + smt * 16 + sq * 4];
    }
    __syncthreads();

    const float4 be2v = *(const float4*)&be2[q * 4];
    const int NT = N_EDGES / 16;
    const int step = gridDim.x * 4;
    const int lbase = lane * 8;           // lds elem offset of this lane's frag pair (per mt: +512)

    int tile = blockIdx.x * 4 + wid;
    if (tile >= NT) return;
    i2 pk = __builtin_nontemporal_load((const i2*)&pack[tile * 16 + l]);   // {src, weight(unused)}
    i2 ec = __builtin_nontemporal_load((const i2*)&eidx[tile * 16 + l]);   // {orig edge, dst}

    for (; tile < NT; tile += step) {
        const int re = pk[0], e = ec[0], ce = ec[1];
        const u16* prow = PQ + (size_t)re * 512 + q * 8;          // P half (random, LLC)
        const u16* qrow = PQ + (size_t)ce * 512 + 256 + q * 8;    // Q half (CSR runs, L1)

        // issue the whole gather batch: attr + 16 wide P/Q loads (16B/lane, 64B/edge/instr)
        f4 av = __builtin_nontemporal_load((const f4*)&attr[(size_t)e * DIM_A + q * 4]);
        s8 pw[8], qw[8];
#pragma unroll
        for (int w = 0; w < 8; w++) {
            pw[w] = *(const s8*)(prow + w * 32);
            qw[w] = *(const s8*)(qrow + w * 32);
        }
        // prefetch next tile's indices (independent of current compute)
        int ntile = tile + step;
        int ns = (ntile < NT) ? ntile * 16 + l : l;
        i2 pk_n = __builtin_nontemporal_load((const i2*)&pack[ns]);
        i2 ec_n = __builtin_nontemporal_load((const i2*)&eidx[ns]);
        // pin: force all batch results live here (IR sinking cannot cross asm operands)
        KEEP4(pw[0], pw[1], pw[2], pw[3]);
        KEEP4(pw[4], pw[5], pw[6], pw[7]);
        KEEP4(qw[0], qw[1], qw[2], qw[3]);
        KEEP4(qw[4], qw[5], qw[6], qw[7]);
        __builtin_amdgcn_sched_barrier(0);

        s4 af = pk_bf16x4(av[0], av[1], av[2], av[3]);   // attr B-frag: B[k=q*4+j][n=edge=l]

        f4 acc2 = {0.f, 0.f, 0.f, 0.f};
#pragma unroll
        for (int w = 0; w < 8; w++) {
#pragma unroll
            for (int s = 0; s < 2; s++) {
                const int mt = w * 2 + s;
                s8 wf = *(const s8*)&lw[mt * 512 + lbase];
                s4 wcf = {wf[0], wf[1], wf[2], wf[3]};
                s4 wef = {wf[4], wf[5], wf[6], wf[7]};
                // C-in = P+Q (layout: reg j <-> row q*4+j, col l — matches D exactly)
                f4 pqs;
                pqs[0] = bf2f((u16)pw[w][s * 4 + 0]) + bf2f((u16)qw[w][s * 4 + 0]);
                pqs[1] = bf2f((u16)pw[w][s * 4 + 1]) + bf2f((u16)qw[w][s * 4 + 1]);
                pqs[2] = bf2f((u16)pw[w][s * 4 + 2]) + bf2f((u16)qw[w][s * 4 + 2]);
                pqs[3] = bf2f((u16)pw[w][s * 4 + 3]) + bf2f((u16)qw[w][s * 4 + 3]);
                f4 acc = __builtin_amdgcn_mfma_f32_16x16x16bf16_1k(wcf, af, pqs, 0, 0, 0);
                s4 uf = pk_bf16x4(fmaxf(acc[0], 0.f), fmaxf(acc[1], 0.f),
                                  fmaxf(acc[2], 0.f), fmaxf(acc[3], 0.f));
                acc2 = __builtin_amdgcn_mfma_f32_16x16x16bf16_1k(wef, uf, acc2, 0, 0, 0);
            }
        }
        // D: col=edge l, row=outcol q*4+r -> one 64B nt store per edge row (scatter via e)
        f4 ov = {acc2[0] + be2v.x, acc2[1] + be2v.y, acc2[2] + be2v.z, acc2[3] + be2v.w};
        __builtin_nontemporal_store(ov, (f4*)&outp[(size_t)e * DIM_A + q * 4]);
        pk = pk_n; ec = ec_n;
    }
}
#else
// Fallback (x32 MFMA + per-wave LDS round-trip), operand-swapped MFMA-2 + float4 store.
#define UPAD 268
__global__ __launch_bounds__(256) void k_edge(const u16* __restrict__ PQ,
                                              const float* __restrict__ attr,
                                              const int2* __restrict__ pack,
                                              const int2* __restrict__ eidx,
                                              const u16* __restrict__ Wct,
                                              const u16* __restrict__ We2t,
                                              const float* __restrict__ be2,
                                              float* __restrict__ outp) {
    __shared__ __align__(16) u16 ub[4][16][UPAD];
    const int tid = threadIdx.x, wid = tid >> 6, lane = tid & 63;
    const int q = lane >> 4, l = lane & 15;
    const float4 be2v = *(const float4*)&be2[q * 4];
    u16(*u)[UPAD] = ub[wid];

    s8 wcf[16];
#pragma unroll
    for (int mt = 0; mt < 16; mt++) {
        wcf[mt] = zero_s8();
        if (q < 2) wcf[mt] = *(const s8*)&Wct[(mt * 16 + l) * 16 + q * 8];
    }

    for (int tile = blockIdx.x * 4 + wid; tile < N_EDGES / 16; tile += gridDim.x * 4) {
        const int s = tile * 16 + l;
        const int2 pk = pack[s];
        const int2 ec = eidx[s];
        const int re = pk.x, e = ec.x, ce = ec.y;
        const u16* prow = PQ + (size_t)re * 512;
        const u16* qrow = PQ + (size_t)ce * 512 + 256;

        s8 af = zero_s8();
        if (q < 2) {
            const float* ap = &attr[(size_t)e * DIM_A + q * 8];
            float4 a0 = *(const float4*)ap;
            float4 a1 = *(const float4*)(ap + 4);
            af[0] = (short)f2bf(a0.x); af[1] = (short)f2bf(a0.y);
            af[2] = (short)f2bf(a0.z); af[3] = (short)f2bf(a0.w);
            af[4] = (short)f2bf(a1.x); af[5] = (short)f2bf(a1.y);
            af[6] = (short)f2bf(a1.z); af[7] = (short)f2bf(a1.w);
        }

#pragma unroll
        for (int mt = 0; mt < 16; mt++) {
            f4 cz = {0.f, 0.f, 0.f, 0.f};
            f4 acc = __builtin_amdgcn_mfma_f32_16x16x32_bf16(wcf[mt], af, cz, 0, 0, 0);
            ushort4 pu = *(const ushort4*)(prow + pq_off(mt, q));
            ushort4 qu = *(const ushort4*)(qrow + pq_off(mt, q));
            float t0 = bf2f(pu.x) + bf2f(qu.x) + acc[0];
            float t1 = bf2f(pu.y) + bf2f(qu.y) + acc[1];
            float t2 = bf2f(pu.z) + bf2f(qu.z) + acc[2];
            float t3 = bf2f(pu.w) + bf2f(qu.w) + acc[3];
            ushort4 o;
            o.x = f2bf(fmaxf(t0, 0.f)); o.y = f2bf(fmaxf(t1, 0.f));
            o.z = f2bf(fmaxf(t2, 0.f)); o.w = f2bf(fmaxf(t3, 0.f));
            *(ushort4*)&u[l][mt * 16 + q * 4] = o;
        }

        f4 acc2 = {0.f, 0.f, 0.f, 0.f};
#pragma unroll
        for (int ks = 0; ks < 8; ks++) {
            s8 uf = *(const s8*)&u[l][ks * 32 + q * 8];
            s8 wf = *(const s8*)&We2t[(size_t)l * DIM_H + ks * 32 + q * 8];
            acc2 = __builtin_amdgcn_mfma_f32_16x16x32_bf16(wf, uf, acc2, 0, 0, 0);
        }
        *(float4*)&outp[(size_t)e * DIM_A + q * 4] =
            make_float4(acc2[0] + be2v.x, acc2[1] + be2v.y,
                        acc2[2] + be2v.z, acc2[3] + be2v.w);
    }
}
#endif

extern "C" void kernel_launch(void* const* d_in, const int* in_sizes, int n_in,
                              void* d_out, int out_size, void* d_ws, size_t ws_size,
                              hipStream_t stream) {
    (void)in_sizes; (void)n_in; (void)out_size; (void)ws_size;
    const float* x    = (const float*)d_in[0];
    const int*   ei   = (const int*)d_in[1];
    const float* attr = (const float*)d_in[2];
    const float* W1   = (const float*)d_in[3];
    const float* b1   = (const float*)d_in[4];
    const float* W2   = (const float*)d_in[5];
    const float* b2   = (const float*)d_in[6];
    const float* Wo1  = (const float*)d_in[7];
    const float* bo1  = (const float*)d_in[8];
    const float* Wo2  = (const float*)d_in[9];
    const float* bo2  = (const float*)d_in[10];
    const float* We1  = (const float*)d_in[11];
    const float* be1  = (const float*)d_in[12];
    const float* We2  = (const float*)d_in[13];
    const float* be2  = (const float*)d_in[14];
    const int* rowi = ei;
    const int* coli = ei + N_EDGES;

    float* hout = (float*)d_out;                       // [N][128]
    float* eout = hout + (size_t)N_NODES * DIM_D;      // [E][16]

    char* ws = (char*)d_ws;
    size_t off = 0;
    auto nxt = [&](size_t b) -> void* {
        void* p = ws + off; off = (off + b + 255) & ~(size_t)255; return p;
    };
    int* cnt    = (int*)nxt((size_t)N_NODES * 4);
    int* startp = (int*)nxt((size_t)(N_NODES + 1) * 4);
    int* cursor = (int*)nxt((size_t)N_NODES * 4);
    int* bsum   = (int*)nxt((size_t)SCAN_BLOCKS * 4);
    int* boff   = (int*)nxt((size_t)SCAN_BLOCKS * 4);
    int2* pack  = (int2*)nxt((size_t)N_EDGES * 8);
    int2* eidx  = (int2*)nxt((size_t)N_EDGES * 8);
    u16* W1t   = (u16*)nxt(128 * 256 * 2);
    u16* W2t   = (u16*)nxt(128 * 256 * 2);
    u16* Wo1t  = (u16*)nxt(128 * 256 * 2);
    u16* Wo2t  = (u16*)nxt(128 * 256 * 2);
    u16* Wabt  = (u16*)nxt(512 * 128 * 2);   // [512][128]: Wa^T | Wb^T
    u16* Wct   = (u16*)nxt(256 * 16 * 2);
    u16* We2t  = (u16*)nxt(16 * 256 * 2);
    float* bpq = (float*)nxt(512 * 4);
    u16* xb    = (u16*)nxt((size_t)N_NODES * DIM_D * 2);     // x cast to bf16
    float* z   = (float*)nxt((size_t)N_NODES * DIM_D * 4);   // Ây accumulator (fp32); layer-1 z (bf16) overlays it
    u16* h1    = (u16*)nxt((size_t)N_NODES * DIM_H * 2);     // intermediate [N][256]
    u16* yb    = (u16*)nxt((size_t)N_NODES * DIM_D * 2);
    // PQ [N][512] bf16 (51.2 MB) overlays z+h1 (both dead once hout is computed)
    u16* PQb = (u16*)z;
    u16* zb  = (u16*)z;    // layer-1 gather output (bf16, 12.8 MB) — dead before gather-2 rewrites z

    const int gE = (N_EDGES + 255) / 256;

    // fused init: all weight transposes + bpq + cnt=0
    k_init<<<(205312 + N_NODES + 255) / 256, 256, 0, stream>>>(
        W1, W2, Wo1, Wo2, We1, We2, be1,
        W1t, W2t, Wo1t, Wo2t, Wabt, Wct, We2t, bpq, cnt);

    // ---- CSR build (hierarchical scan: was a 125 µs single-block kernel) ----
    k_count<<<gE, 256, 0, stream>>>(coli, cnt);
    k_scan1<<<SCAN_BLOCKS, 256, 0, stream>>>(cnt, startp, bsum);
    k_scan2<<<1, 256, 0, stream>>>(bsum, boff, startp);
    k_scan3<<<SCAN_BLOCKS, 256, 0, stream>>>(startp, boff, cursor);
    k_fill<<<gE, 256, 0, stream>>>(rowi, coli, cnt, cursor, pack, eidx);

    // cast x -> bf16 (halves layer-1 gather traffic)
    k_cast<<<(N_NODES * DIM_D / 4 + 255) / 256, 256, 0, stream>>>(x, xb, N_NODES * DIM_D / 4);

    const int gG = (N_NODES + 3) / 4;   // 4 nodes (waves) per block
    // layer 1: zb = Âx (bf16) ; h1 = relu(zb@W1 + b1)   [BN=128]
    k_gather<true><<<gG, 256, 0, stream>>>(xb, pack, startp, cnt, zb);
    k_gemm<128, true, false, true, true, false><<<dim3(391, 2), 256, 0, stream>>>(zb, W1t, nullptr, b1, h1, N_NODES, 128, 256);
    // layer 2: y = h1@W2 ; z = Ây (fp32) ; h2 = relu(z + b2) fused into next GEMM's A-stage
    k_gemm<64, true, false, false, true, false><<<dim3(391, 2), 256, 0, stream>>>(h1, W2t, nullptr, nullptr, yb, N_NODES, 256, 128);
    k_gather<false><<<gG, 256, 0, stream>>>(yb, pack, startp, cnt, z);
    // output MLP: h3 = relu(relu(z+b2)@Wo1 + bo1) ; h = h3@Wo2 + bo2 -> d_out (fp32)
    k_gemm<128, false, true, true, true, false><<<dim3(391, 2), 256, 0, stream>>>(z, Wo1t, b2, bo1, h1, N_NODES, 128, 256);
    k_gemm<64, true, false, false, false, false><<<dim3(391, 2), 256, 0, stream>>>(h1, Wo2t, nullptr, bo2, hout, N_NODES, 256, 128);
    // edge predictor precompute: PQ = [h@Wa + be1 | h@Wb]  (bf16, [N][512], permuted cols)
    k_gemm<128, false, false, false, true, true><<<dim3(391, 4), 256, 0, stream>>>(hout, Wabt, nullptr, bpq, PQb, N_NODES, 128, 512);
    // per-edge (CSR slot order): out = relu(P[src]+Q[dst]+attr@Wc)@We2 + be2
    k_edge<<<2048, 256, 0, stream>>>(PQb, attr, pack, eidx, Wct, We2t, be2, eout);
}

// Round 10
// 564.290 us; speedup vs baseline: 1.2031x; 1.0073x over previous
//
#include <hip/hip_runtime.h>
#include <hip/hip_bf16.h>

// Problem constants (from reference): N=50000, E=800000, D=128, H=256, A=16
#define N_NODES 50000
#define N_EDGES 800000
#define DIM_D   128
#define DIM_H   256
#define DIM_A   16

typedef unsigned short u16;
typedef __attribute__((ext_vector_type(4))) float f4;
typedef __attribute__((ext_vector_type(8))) short s8;
typedef __attribute__((ext_vector_type(4))) short s4;
typedef __attribute__((ext_vector_type(4))) int i4;

__device__ __forceinline__ u16 f2bf(float f) {
    union { float f; unsigned u; } v; v.f = f;
    unsigned r = v.u + 0x7FFFu + ((v.u >> 16) & 1u);   // RNE
    return (u16)(r >> 16);
}
__device__ __forceinline__ float bf2f(u16 s) {
    union { unsigned u; float f; } v; v.u = ((unsigned)s) << 16; return v.f;
}
__device__ __forceinline__ s8 zero_s8() {
    s8 v;
#pragma unroll
    for (int i = 0; i < 8; i++) v[i] = 0;
    return v;
}
// HW-packed f32->bf16 via HIP intrinsics (compiler emits v_cvt_pk_bf16_f32; RNE, no inline asm)
__device__ __forceinline__ s4 pk_bf16x4(float a, float b, float c, float d) {
    __hip_bfloat162 h0 = __float22bfloat162_rn(make_float2(a, b));
    __hip_bfloat162 h1 = __float22bfloat162_rn(make_float2(c, d));
    s4 v;
    __builtin_memcpy(&v, &h0, 4);
    __builtin_memcpy(((char*)&v) + 4, &h1, 4);
    return v;
}
__device__ __forceinline__ u16 f2bf_hw(float f) {
    __hip_bfloat16 h = __float2bfloat16(f);
    u16 u; __builtin_memcpy(&u, &h, 2);
    return u;
}

// ---- PQ permuted column layout (within each 64-col group of a PQ row) ----
// stored[i*32 + q*8 + s*4 + j] = logical[(2i+s)*16 + q*4 + j]
__device__ __forceinline__ int pq_off(int mt, int q) {   // stored elem offset of logical chunk (mt, q)
    return (mt >> 2) * 64 + ((mt >> 1) & 1) * 32 + q * 8 + (mt & 1) * 4;
}

// ---------------- fused init: weight transposes + bpq + cnt zero + x->bf16 cast ------------
#define INIT_W   205312                   // weights (204800) + bpq (512)
#define INIT_C   (INIT_W + N_NODES)       // + cnt zero
#define INIT_X   (INIT_C + N_NODES * DIM_D / 4)   // + x cast (4 floats per thread)
__global__ __launch_bounds__(256) void k_init(const float* __restrict__ W1, const float* __restrict__ W2,
                                              const float* __restrict__ Wo1, const float* __restrict__ Wo2,
                                              const float* __restrict__ We1, const float* __restrict__ We2,
                                              const float* __restrict__ be1, const float* __restrict__ x,
                                              u16* __restrict__ W1t, u16* __restrict__ W2t,
                                              u16* __restrict__ Wo1t, u16* __restrict__ Wo2t,
                                              u16* __restrict__ Wabt, u16* __restrict__ Wct,
                                              u16* __restrict__ We2t, float* __restrict__ bpq,
                                              int* __restrict__ cnt, u16* __restrict__ xb) {
    int idx = blockIdx.x * 256 + threadIdx.x;
    if (idx < 32768) {                 // W1 [128][256] -> W1t [256][128]
        int k = idx >> 8, n = idx & 255;
        W1t[n * 128 + k] = f2bf(W1[idx]);
    } else if (idx < 65536) {          // W2 [256][128] -> W2t [128][256]
        int r = idx - 32768, k = r >> 7, n = r & 127;
        W2t[n * 256 + k] = f2bf(W2[r]);
    } else if (idx < 98304) {          // Wo1 [128][256] -> Wo1t [256][128]
        int r = idx - 65536, k = r >> 8, n = r & 255;
        Wo1t[n * 128 + k] = f2bf(Wo1[r]);
    } else if (idx < 131072) {         // Wo2 [256][128] -> Wo2t [128][256]
        int r = idx - 98304, k = r >> 7, n = r & 127;
        Wo2t[n * 256 + k] = f2bf(Wo2[r]);
    } else if (idx < 163840) {         // Wa = We1 rows 0..127 -> Wabt[0..]
        int r = idx - 131072, k = r >> 8, n = r & 255;
        Wabt[n * 128 + k] = f2bf(We1[r]);
    } else if (idx < 196608) {         // Wb = We1 rows 128..255 -> Wabt[32768..]
        int r = idx - 163840, k = r >> 8, n = r & 255;
        Wabt[32768 + n * 128 + k] = f2bf(We1[32768 + r]);
    } else if (idx < 200704) {         // Wc = We1 rows 256..271 [16][256] -> Wct [256][16]
        int r = idx - 196608, k = r >> 8, n = r & 255;
        Wct[n * 16 + k] = f2bf(We1[65536 + r]);
    } else if (idx < 204800) {         // We2 [256][16] -> We2t [16][256]
        int r = idx - 200704, k = r >> 4, n = r & 15;
        We2t[n * 256 + k] = f2bf(We2[r]);
    } else if (idx < INIT_W) {         // bpq
        int i = idx - 204800;
        bpq[i] = (i < 256) ? be1[i] : 0.f;
    } else if (idx < INIT_C) {
        cnt[idx - INIT_W] = 0;
    } else if (idx < INIT_X) {         // x -> bf16 (4 floats per thread)
        int i = idx - INIT_C;
        f4 v = __builtin_nontemporal_load((const f4*)&x[(size_t)i * 4]);
        ushort4 o;
        o.x = f2bf(v[0]); o.y = f2bf(v[1]); o.z = f2bf(v[2]); o.w = f2bf(v[3]);
        *(ushort4*)&xb[(size_t)i * 4] = o;
    }
}

// ---------------- CSR build ----------------
__global__ __launch_bounds__(256) void k_count(const int* __restrict__ coli, int* __restrict__ cnt) {
    int e = blockIdx.x * 256 + threadIdx.x;
    if (e < N_EDGES) atomicAdd(&cnt[__builtin_nontemporal_load(&coli[e])], 1);
}

// ---- hierarchical scan (round-8 PMC: single-block scan was 125 µs — one CU, uncoalesced) ----
#define SCAN_BLOCKS 196   // 196*256 = 50176 >= N_NODES

__global__ __launch_bounds__(256) void k_scan1(const int* __restrict__ cnt, int* __restrict__ start,
                                               int* __restrict__ bsum) {
    __shared__ int ps[256];
    int t = threadIdx.x, idx = blockIdx.x * 256 + t;
    int v = (idx < N_NODES) ? cnt[idx] : 0;
    ps[t] = v;
    __syncthreads();
    for (int ofs = 1; ofs < 256; ofs <<= 1) {
        int u = (t >= ofs) ? ps[t - ofs] : 0;
        __syncthreads();
        ps[t] += u;
        __syncthreads();
    }
    if (idx < N_NODES) start[idx] = ps[t] - v;     // local exclusive
    if (t == 255) bsum[blockIdx.x] = ps[255];
}
__global__ __launch_bounds__(256) void k_scan2(const int* __restrict__ bsum, int* __restrict__ boff,
                                               int* __restrict__ start) {
    __shared__ int ps[256];
    int t = threadIdx.x;
    int v = (t < SCAN_BLOCKS) ? bsum[t] : 0;
    ps[t] = v;
    __syncthreads();
    for (int ofs = 1; ofs < 256; ofs <<= 1) {
        int u = (t >= ofs) ? ps[t - ofs] : 0;
        __syncthreads();
        ps[t] += u;
        __syncthreads();
    }
    if (t < SCAN_BLOCKS) boff[t] = ps[t] - v;
    if (t == 255) start[N_NODES] = ps[255];
}
__global__ __launch_bounds__(256) void k_scan3(int* __restrict__ start, const int* __restrict__ boff,
                                               int* __restrict__ cursor) {
    int idx = blockIdx.x * 256 + threadIdx.x;
    if (idx >= N_NODES) return;
    int s = start[idx] + boff[blockIdx.x];
    start[idx] = s;
    cursor[idx] = s;
}

// pe[slot] = {src, dinv[src]*dinv[dst], orig_edge, dst} — single 16B scattered store (was two
// 8B stores to two regions = two cache-line touches per edge)
__global__ __launch_bounds__(256) void k_fill(const int* __restrict__ rowi, const int* __restrict__ coli,
                                              const int* __restrict__ cnt,
                                              int* __restrict__ cursor, i4* __restrict__ pe) {
    int e = blockIdx.x * 256 + threadIdx.x;
    if (e >= N_EDGES) return;
    int r = __builtin_nontemporal_load(&rowi[e]);
    int c = __builtin_nontemporal_load(&coli[e]);
    int slot = atomicAdd(&cursor[c], 1);
    float w = rsqrtf((float)(cnt[r] + 1)) * rsqrtf((float)(cnt[c] + 1));
    i4 v = {r, __float_as_int(w), e, c};
    __builtin_nontemporal_store(v, &pe[slot]);
}

// ---------------- CSR gather: z[n] = X[n]*dinv[n]^2 + sum_{e->n} X[src]*w ----------------
// OB: write bf16. 8-deep pipeline (avg half-span ~8 => whole span in one batch of in-flight loads)
template <bool OB>
__global__ __launch_bounds__(256) void k_gather(const u16* __restrict__ X,
                                                const i4* __restrict__ pe,
                                                const int* __restrict__ start,
                                                const int* __restrict__ cnt,
                                                void* __restrict__ zout) {
    int node = blockIdx.x * 4 + (threadIdx.x >> 6);
    if (node >= N_NODES) return;
    int lane = threadIdx.x & 63;
    int half = lane >> 5, j = lane & 31;
    int c4 = j * 4;
    float di = rsqrtf((float)(cnt[node] + 1));
    f4 acc = {0.f, 0.f, 0.f, 0.f};
    if (half == 0) {
        float sl = di * di;
        ushort4 u = *(const ushort4*)&X[(size_t)node * DIM_D + c4];
        acc[0] = bf2f(u.x) * sl; acc[1] = bf2f(u.y) * sl;
        acc[2] = bf2f(u.z) * sl; acc[3] = bf2f(u.w) * sl;
    }
    int s0 = start[node], e0 = start[node + 1];
    int h0 = (e0 - s0 + 1) >> 1;
    int i   = half ? (s0 + h0) : s0;
    int end = half ? e0 : (s0 + h0);
    // 8-deep: 8 independent pe loads, then 8 row loads in flight
    for (; i + 7 < end; i += 8) {
        i4 p[8];
        ushort4 u[8];
#pragma unroll
        for (int t = 0; t < 8; t++) p[t] = __builtin_nontemporal_load(&pe[i + t]);
#pragma unroll
        for (int t = 0; t < 8; t++) u[t] = *(const ushort4*)&X[(size_t)p[t][0] * DIM_D + c4];
#pragma unroll
        for (int t = 0; t < 8; t++) {
            float w = __int_as_float(p[t][1]);
            acc[0] += bf2f(u[t].x) * w; acc[1] += bf2f(u[t].y) * w;
            acc[2] += bf2f(u[t].z) * w; acc[3] += bf2f(u[t].w) * w;
        }
    }
    for (; i + 3 < end; i += 4) {
        i4 p[4];
        ushort4 u[4];
#pragma unroll
        for (int t = 0; t < 4; t++) p[t] = __builtin_nontemporal_load(&pe[i + t]);
#pragma unroll
        for (int t = 0; t < 4; t++) u[t] = *(const ushort4*)&X[(size_t)p[t][0] * DIM_D + c4];
#pragma unroll
        for (int t = 0; t < 4; t++) {
            float w = __int_as_float(p[t][1]);
            acc[0] += bf2f(u[t].x) * w; acc[1] += bf2f(u[t].y) * w;
            acc[2] += bf2f(u[t].z) * w; acc[3] += bf2f(u[t].w) * w;
        }
    }
    for (; i < end; i++) {
        i4 p = __builtin_nontemporal_load(&pe[i]);
        float w = __int_as_float(p[1]);
        ushort4 u = *(const ushort4*)&X[(size_t)p[0] * DIM_D + c4];
        acc[0] += bf2f(u.x) * w; acc[1] += bf2f(u.y) * w;
        acc[2] += bf2f(u.z) * w; acc[3] += bf2f(u.w) * w;
    }
    // combine halves: lane j (<32) += lane j+32
    float t0 = acc[0] + __shfl(acc[0], j + 32);
    float t1 = acc[1] + __shfl(acc[1], j + 32);
    float t2 = acc[2] + __shfl(acc[2], j + 32);
    float t3 = acc[3] + __shfl(acc[3], j + 32);
    if (half == 0) {
        if (OB) {
            s4 o = pk_bf16x4(t0, t1, t2, t3);
            *(s4*)&((u16*)zout)[(size_t)node * DIM_D + c4] = o;
        } else {
            *(float4*)&((float*)zout)[(size_t)node * DIM_D + c4] = make_float4(t0, t1, t2, t3);
        }
    }
}

// ---------------- MFMA GEMM: C[M][Nn] = post(A[M][K] @ W + postB), W given as Wt[Nn][K] bf16 ----
#define BM 128
#define BK 32
#define BKP 56   // padded K stride in LDS (bf16 elems)

template <int BNv, bool A_BF16, bool PRE_BR, bool POST_RELU, bool OUT_BF16, bool PERM_PQ>
__global__ __launch_bounds__(256) void k_gemm(const void* __restrict__ Ap,
                                              const u16* __restrict__ Wt,
                                              const float* __restrict__ preB,
                                              const float* __restrict__ postB,
                                              void* __restrict__ Cp,
                                              int M, int K, int Nn) {
    constexpr int BNT = BNv / 16;            // 16x16 col-tiles per wave row
    __shared__ __align__(16) u16 As[BM * BKP];
    __shared__ __align__(16) u16 Bs[BNv * BKP];
    const int tid = threadIdx.x;
    const int wid = tid >> 6, lane = tid & 63;
    const int q = lane >> 4, l = lane & 15;
    const int bm = blockIdx.x * BM, bn = blockIdx.y * BNv;

    f4 acc[2 * BNT];
#pragma unroll
    for (int i = 0; i < 2 * BNT; i++) { f4 zz = {0.f, 0.f, 0.f, 0.f}; acc[i] = zz; }

    for (int k0 = 0; k0 < K; k0 += BK) {
        __syncthreads();
        // stage W tile: Bs[n][k], n in [bn,bn+BNv), k in [k0,k0+32)
#pragma unroll
        for (int p = 0; p < BNv / 64; p++) {
            int n = (tid >> 2) + p * 64, kc = (tid & 3) * 8;
            *(int4*)&Bs[n * BKP + kc] = *(const int4*)&Wt[(size_t)(bn + n) * K + k0 + kc];
        }
        // stage A tile: As[m][k]
        if (A_BF16) {
            const u16* A = (const u16*)Ap;
#pragma unroll
            for (int p = 0; p < 2; p++) {
                int m = (tid >> 2) + p * 64, kc = (tid & 3) * 8;
                int gm = bm + m; if (gm >= M) gm = M - 1;
                *(int4*)&As[m * BKP + kc] = *(const int4*)&A[(size_t)gm * K + k0 + kc];
            }
        } else {
            const float* A = (const float*)Ap;
#pragma unroll
            for (int p = 0; p < 4; p++) {
                int m = (tid >> 3) + p * 32, k4 = (tid & 7) * 4;
                int gm = bm + m; if (gm >= M) gm = M - 1;
                float4 v = *(const float4*)&A[(size_t)gm * K + k0 + k4];
                if (PRE_BR) {
                    const float4 pb = *(const float4*)&preB[k0 + k4];
                    v.x = fmaxf(v.x + pb.x, 0.f);
                    v.y = fmaxf(v.y + pb.y, 0.f);
                    v.z = fmaxf(v.z + pb.z, 0.f);
                    v.w = fmaxf(v.w + pb.w, 0.f);
                }
                s4 o = pk_bf16x4(v.x, v.y, v.z, v.w);
                *(s4*)&As[m * BKP + k4] = o;
            }
        }
        __syncthreads();

        s8 af[2], bf[BNT];
#pragma unroll
        for (int mt = 0; mt < 2; mt++)
            af[mt] = *(const s8*)&As[(wid * 32 + mt * 16 + l) * BKP + q * 8];
#pragma unroll
        for (int nt = 0; nt < BNT; nt++)
            bf[nt] = *(const s8*)&Bs[(nt * 16 + l) * BKP + q * 8];
#pragma unroll
        for (int mt = 0; mt < 2; mt++)
#pragma unroll
            for (int nt = 0; nt < BNT; nt++)
                acc[mt * BNT + nt] = __builtin_amdgcn_mfma_f32_16x16x32_bf16(
                    af[mt], bf[nt], acc[mt * BNT + nt], 0, 0, 0);
    }

    // epilogue: C row = q*4+r, col = l (per 16x16 tile)
#pragma unroll
    for (int mt = 0; mt < 2; mt++) {
#pragma unroll
        for (int nt = 0; nt < BNT; nt++) {
            int colg = bn + nt * 16 + l;                // logical col (bias index)
            float pb = postB ? postB[colg] : 0.0f;
            int cols = colg;
            if (PERM_PQ) {
                int w = colg & 63, mtL = w >> 4;
                cols = (colg & ~63) | (((mtL >> 1) & 1) * 32) | (((w >> 2) & 3) * 8)
                       | ((mtL & 1) * 4) | (w & 3);
            }
#pragma unroll
            for (int r = 0; r < 4; r++) {
                int rowg = bm + wid * 32 + mt * 16 + q * 4 + r;
                if (rowg < M) {
                    float v = acc[mt * BNT + nt][r] + pb;
                    if (POST_RELU) v = fmaxf(v, 0.f);
                    if (OUT_BF16)
                        ((u16*)Cp)[(size_t)rowg * Nn + cols] = f2bf_hw(v);
                    else
                        ((float*)Cp)[(size_t)rowg * Nn + cols] = v;
                }
            }
        }
    }
}

// ---------------- edge predictor: 16 edges (CSR slots) per wave -----------------------------
// FROZEN logic (v8) + merged pe index array (one 16B load instead of two 8B).
#if __has_builtin(__builtin_amdgcn_mfma_f32_16x16x16bf16_1k)
#define KEEP4(a,b,c,d) asm volatile("" :: "v"(a), "v"(b), "v"(c), "v"(d))
__global__ __launch_bounds__(256) void k_edge(const u16* __restrict__ PQ,     // [N][512]: P|Q (permuted)
                                              const float* __restrict__ attr,
                                              const i4* __restrict__ pe,
                                              const u16* __restrict__ Wct,    // [256][16] bf16
                                              const u16* __restrict__ We2t,   // [16][256] bf16
                                              const float* __restrict__ be2,
                                              float* __restrict__ outp) {
    // interleaved weight table: [mt][lane=q*16+l] x {wc frag (4 u16), we frag (4 u16)} = 16 KB
    __shared__ __align__(16) u16 lw[16 * 64 * 8];
    const int tid = threadIdx.x, wid = tid >> 6, lane = tid & 63;
    const int q = lane >> 4, l = lane & 15;
    for (int u = tid; u < 1024; u += 256) {
        int smt = u >> 6, sq = (u >> 4) & 3, sl = u & 15;
        *(uint2*)&lw[u * 8]     = *(const uint2*)&Wct[(smt * 16 + sl) * 16 + sq * 4];
        *(uint2*)&lw[u * 8 + 4] = *(const uint2*)&We2t[sl * DIM_H + smt * 16 + sq * 4];
    }
    __syncthreads();

    const float4 be2v = *(const float4*)&be2[q * 4];
    const int NT = N_EDGES / 16;
    const int step = gridDim.x * 4;
    const int lbase = lane * 8;           // lds elem offset of this lane's frag pair (per mt: +512)

    int tile = blockIdx.x * 4 + wid;
    if (tile >= NT) return;
    i4 pk = __builtin_nontemporal_load(&pe[tile * 16 + l]);   // {src, w, edge, dst}

    for (; tile < NT; tile += step) {
        const int re = pk[0], e = pk[2], ce = pk[3];
        const u16* prow = PQ + (size_t)re * 512 + q * 8;          // P half (random, LLC)
        const u16* qrow = PQ + (size_t)ce * 512 + 256 + q * 8;    // Q half (CSR runs, L1)

        // issue the whole gather batch: attr + 16 wide P/Q loads (16B/lane, 64B/edge/instr)
        f4 av = __builtin_nontemporal_load((const f4*)&attr[(size_t)e * DIM_A + q * 4]);
        s8 pw[8], qw[8];
#pragma unroll
        for (int w = 0; w < 8; w++) {
            pw[w] = *(const s8*)(prow + w * 32);
            qw[w] = *(const s8*)(qrow + w * 32);
        }
        // prefetch next tile's indices (independent of current compute)
        int ntile = tile + step;
        int ns = (ntile < NT) ? ntile * 16 + l : l;
        i4 pk_n = __builtin_nontemporal_load(&pe[ns]);
        // pin: force all batch results live here (IR sinking cannot cross asm operands)
        KEEP4(pw[0], pw[1], pw[2], pw[3]);
        KEEP4(pw[4], pw[5], pw[6], pw[7]);
        KEEP4(qw[0], qw[1], qw[2], qw[3]);
        KEEP4(qw[4], qw[5], qw[6], qw[7]);
        __builtin_amdgcn_sched_barrier(0);

        s4 af = pk_bf16x4(av[0], av[1], av[2], av[3]);   // attr B-frag: B[k=q*4+j][n=edge=l]

        f4 acc2 = {0.f, 0.f, 0.f, 0.f};
#pragma unroll
        for (int w = 0; w < 8; w++) {
#pragma unroll
            for (int s = 0; s < 2; s++) {
                const int mt = w * 2 + s;
                s8 wf = *(const s8*)&lw[mt * 512 + lbase];
                s4 wcf = {wf[0], wf[1], wf[2], wf[3]};
                s4 wef = {wf[4], wf[5], wf[6], wf[7]};
                // C-in = P+Q (layout: reg j <-> row q*4+j, col l — matches D exactly)
                f4 pqs;
                pqs[0] = bf2f((u16)pw[w][s * 4 + 0]) + bf2f((u16)qw[w][s * 4 + 0]);
                pqs[1] = bf2f((u16)pw[w][s * 4 + 1]) + bf2f((u16)qw[w][s * 4 + 1]);
                pqs[2] = bf2f((u16)pw[w][s * 4 + 2]) + bf2f((u16)qw[w][s * 4 + 2]);
                pqs[3] = bf2f((u16)pw[w][s * 4 + 3]) + bf2f((u16)qw[w][s * 4 + 3]);
                f4 acc = __builtin_amdgcn_mfma_f32_16x16x16bf16_1k(wcf, af, pqs, 0, 0, 0);
                s4 uf = pk_bf16x4(fmaxf(acc[0], 0.f), fmaxf(acc[1], 0.f),
                                  fmaxf(acc[2], 0.f), fmaxf(acc[3], 0.f));
                acc2 = __builtin_amdgcn_mfma_f32_16x16x16bf16_1k(wef, uf, acc2, 0, 0, 0);
            }
        }
        // D: col=edge l, row=outcol q*4+r -> one 64B nt store per edge row (scatter via e)
        f4 ov = {acc2[0] + be2v.x, acc2[1] + be2v.y, acc2[2] + be2v.z, acc2[3] + be2v.w};
        __builtin_nontemporal_store(ov, (f4*)&outp[(size_t)e * DIM_A + q * 4]);
        pk = pk_n;
    }
}
#else
// Fallback (x32 MFMA + per-wave LDS round-trip), operand-swapped MFMA-2 + float4 store.
#define UPAD 268
__global__ __launch_bounds__(256) void k_edge(const u16* __restrict__ PQ,
                                              const float* __restrict__ attr,
                                              const i4* __restrict__ pe,
                                              const u16* __restrict__ Wct,
                                              const u16* __restrict__ We2t,
                                              const float* __restrict__ be2,
                                              float* __restrict__ outp) {
    __shared__ __align__(16) u16 ub[4][16][UPAD];
    const int tid = threadIdx.x, wid = tid >> 6, lane = tid & 63;
    const int q = lane >> 4, l = lane & 15;
    const float4 be2v = *(const float4*)&be2[q * 4];
    u16(*u)[UPAD] = ub[wid];

    s8 wcf[16];
#pragma unroll
    for (int mt = 0; mt < 16; mt++) {
        wcf[mt] = zero_s8();
        if (q < 2) wcf[mt] = *(const s8*)&Wct[(mt * 16 + l) * 16 + q * 8];
    }

    for (int tile = blockIdx.x * 4 + wid; tile < N_EDGES / 16; tile += gridDim.x * 4) {
        const int s = tile * 16 + l;
        const i4 pk = pe[s];
        const int re = pk[0], e = pk[2], ce = pk[3];
        const u16* prow = PQ + (size_t)re * 512;
        const u16* qrow = PQ + (size_t)ce * 512 + 256;

        s8 af = zero_s8();
        if (q < 2) {
            const float* ap = &attr[(size_t)e * DIM_A + q * 8];
            float4 a0 = *(const float4*)ap;
            float4 a1 = *(const float4*)(ap + 4);
            af[0] = (short)f2bf(a0.x); af[1] = (short)f2bf(a0.y);
            af[2] = (short)f2bf(a0.z); af[3] = (short)f2bf(a0.w);
            af[4] = (short)f2bf(a1.x); af[5] = (short)f2bf(a1.y);
            af[6] = (short)f2bf(a1.z); af[7] = (short)f2bf(a1.w);
        }

#pragma unroll
        for (int mt = 0; mt < 16; mt++) {
            f4 cz = {0.f, 0.f, 0.f, 0.f};
            f4 acc = __builtin_amdgcn_mfma_f32_16x16x32_bf16(wcf[mt], af, cz, 0, 0, 0);
            ushort4 pu = *(const ushort4*)(prow + pq_off(mt, q));
            ushort4 qu = *(const ushort4*)(qrow + pq_off(mt, q));
            float t0 = bf2f(pu.x) + bf2f(qu.x) + acc[0];
            float t1 = bf2f(pu.y) + bf2f(qu.y) + acc[1];
            float t2 = bf2f(pu.z) + bf2f(qu.z) + acc[2];
            float t3 = bf2f(pu.w) + bf2f(qu.w) + acc[3];
            ushort4 o;
            o.x = f2bf(fmaxf(t0, 0.f)); o.y = f2bf(fmaxf(t1, 0.f));
            o.z = f2bf(fmaxf(t2, 0.f)); o.w = f2bf(fmaxf(t3, 0.f));
            *(ushort4*)&u[l][mt * 16 + q * 4] = o;
        }

        f4 acc2 = {0.f, 0.f, 0.f, 0.f};
#pragma unroll
        for (int ks = 0; ks < 8; ks++) {
            s8 uf = *(const s8*)&u[l][ks * 32 + q * 8];
            s8 wf = *(const s8*)&We2t[(size_t)l * DIM_H + ks * 32 + q * 8];
            acc2 = __builtin_amdgcn_mfma_f32_16x16x32_bf16(wf, uf, acc2, 0, 0, 0);
        }
        *(float4*)&outp[(size_t)e * DIM_A + q * 4] =
            make_float4(acc2[0] + be2v.x, acc2[1] + be2v.y,
                        acc2[2] + be2v.z, acc2[3] + be2v.w);
    }
}
#endif

extern "C" void kernel_launch(void* const* d_in, const int* in_sizes, int n_in,
                              void* d_out, int out_size, void* d_ws, size_t ws_size,
                              hipStream_t stream) {
    (void)in_sizes; (void)n_in; (void)out_size; (void)ws_size;
    const float* x    = (const float*)d_in[0];
    const int*   ei   = (const int*)d_in[1];
    const float* attr = (const float*)d_in[2];
    const float* W1   = (const float*)d_in[3];
    const float* b1   = (const float*)d_in[4];
    const float* W2   = (const float*)d_in[5];
    const float* b2   = (const float*)d_in[6];
    const float* Wo1  = (const float*)d_in[7];
    const float* bo1  = (const float*)d_in[8];
    const float* Wo2  = (const float*)d_in[9];
    const float* bo2  = (const float*)d_in[10];
    const float* We1  = (const float*)d_in[11];
    const float* be1  = (const float*)d_in[12];
    const float* We2  = (const float*)d_in[13];
    const float* be2  = (const float*)d_in[14];
    const int* rowi = ei;
    const int* coli = ei + N_EDGES;

    float* hout = (float*)d_out;                       // [N][128]
    float* eout = hout + (size_t)N_NODES * DIM_D;      // [E][16]

    char* ws = (char*)d_ws;
    size_t off = 0;
    auto nxt = [&](size_t b) -> void* {
        void* p = ws + off; off = (off + b + 255) & ~(size_t)255; return p;
    };
    int* cnt    = (int*)nxt((size_t)N_NODES * 4);
    int* startp = (int*)nxt((size_t)(N_NODES + 1) * 4);
    int* cursor = (int*)nxt((size_t)N_NODES * 4);
    int* bsum   = (int*)nxt((size_t)SCAN_BLOCKS * 4);
    int* boff   = (int*)nxt((size_t)SCAN_BLOCKS * 4);
    i4* pe      = (i4*)nxt((size_t)N_EDGES * 16);
    u16* W1t   = (u16*)nxt(128 * 256 * 2);
    u16* W2t   = (u16*)nxt(128 * 256 * 2);
    u16* Wo1t  = (u16*)nxt(128 * 256 * 2);
    u16* Wo2t  = (u16*)nxt(128 * 256 * 2);
    u16* Wabt  = (u16*)nxt(512 * 128 * 2);   // [512][128]: Wa^T | Wb^T
    u16* Wct   = (u16*)nxt(256 * 16 * 2);
    u16* We2t  = (u16*)nxt(16 * 256 * 2);
    float* bpq = (float*)nxt(512 * 4);
    u16* xb    = (u16*)nxt((size_t)N_NODES * DIM_D * 2);     // x cast to bf16
    float* z   = (float*)nxt((size_t)N_NODES * DIM_D * 4);   // Ây accumulator (fp32); layer-1 z (bf16) overlays it
    u16* h1    = (u16*)nxt((size_t)N_NODES * DIM_H * 2);     // intermediate [N][256]
    u16* yb    = (u16*)nxt((size_t)N_NODES * DIM_D * 2);
    // PQ [N][512] bf16 (51.2 MB) overlays z+h1 (both dead once hout is computed)
    u16* PQb = (u16*)z;
    u16* zb  = (u16*)z;    // layer-1 gather output (bf16, 12.8 MB) — dead before gather-2 rewrites z

    const int gE = (N_EDGES + 255) / 256;

    // fused init: weight transposes + bpq + cnt=0 + x->bf16 cast
    k_init<<<(INIT_X + 255) / 256, 256, 0, stream>>>(
        W1, W2, Wo1, Wo2, We1, We2, be1, x,
        W1t, W2t, Wo1t, Wo2t, Wabt, Wct, We2t, bpq, cnt, xb);

    // ---- CSR build (hierarchical scan) ----
    k_count<<<gE, 256, 0, stream>>>(coli, cnt);
    k_scan1<<<SCAN_BLOCKS, 256, 0, stream>>>(cnt, startp, bsum);
    k_scan2<<<1, 256, 0, stream>>>(bsum, boff, startp);
    k_scan3<<<SCAN_BLOCKS, 256, 0, stream>>>(startp, boff, cursor);
    k_fill<<<gE, 256, 0, stream>>>(rowi, coli, cnt, cursor, pe);

    const int gG = (N_NODES + 3) / 4;   // 4 nodes (waves) per block
    // layer 1: zb = Âx (bf16) ; h1 = relu(zb@W1 + b1)   [BN=128]
    k_gather<true><<<gG, 256, 0, stream>>>(xb, pe, startp, cnt, zb);
    k_gemm<128, true, false, true, true, false><<<dim3(391, 2), 256, 0, stream>>>(zb, W1t, nullptr, b1, h1, N_NODES, 128, 256);
    // layer 2: y = h1@W2 ; z = Ây (fp32) ; h2 = relu(z + b2) fused into next GEMM's A-stage
    k_gemm<64, true, false, false, true, false><<<dim3(391, 2), 256, 0, stream>>>(h1, W2t, nullptr, nullptr, yb, N_NODES, 256, 128);
    k_gather<false><<<gG, 256, 0, stream>>>(yb, pe, startp, cnt, z);
    // output MLP: h3 = relu(relu(z+b2)@Wo1 + bo1) ; h = h3@Wo2 + bo2 -> d_out (fp32)
    k_gemm<128, false, true, true, true, false><<<dim3(391, 2), 256, 0, stream>>>(z, Wo1t, b2, bo1, h1, N_NODES, 128, 256);
    k_gemm<64, true, false, false, false, false><<<dim3(391, 2), 256, 0, stream>>>(h1, Wo2t, nullptr, bo2, hout, N_NODES, 256, 128);
    // edge predictor precompute: PQ = [h@Wa + be1 | h@Wb]  (bf16, [N][512], permuted cols)
    k_gemm<128, false, false, false, true, true><<<dim3(391, 4), 256, 0, stream>>>(hout, Wabt, nullptr, bpq, PQb, N_NODES, 128, 512);
    // per-edge (CSR slot order): out = relu(P[src]+Q[dst]+attr@Wc)@We2 + be2
    k_edge<<<2048, 256, 0, stream>>>(PQb, attr, pe, Wct, We2t, be2, eout);
}